// Round 7
// baseline (409.131 us; speedup 1.0000x reference)
//
#include <hip/hip_runtime.h>
#include <hip/hip_bf16.h>
#include <stdint.h>

using f32x4   = __attribute__((ext_vector_type(4))) float;
using half8   = __attribute__((ext_vector_type(8))) _Float16;
using half4   = __attribute__((ext_vector_type(4))) _Float16;
using float4v = __attribute__((ext_vector_type(4))) float;

typedef const __attribute__((address_space(1))) void gas_void;
typedef __attribute__((address_space(3))) void las_void;

__device__ __forceinline__ void gload_lds16(const void* gptr, void* lptr) {
  __builtin_amdgcn_global_load_lds((gas_void*)(uintptr_t)gptr,
                                   (las_void*)(uintptr_t)lptr, 16, 0, 0);
}

#define MFMA_F16(a, b, c) __builtin_amdgcn_mfma_f32_16x16x32_f16((a), (b), (c), 0, 0, 0)

// ---------- weights fp32->fp16: w16 (2304x768), wp16, wvT (grid-stride) ----------
__global__ void k_cvtw(const float* __restrict__ wqkv, const float* __restrict__ wproj,
                       _Float16* __restrict__ w16, _Float16* __restrict__ wp16,
                       _Float16* __restrict__ wvT) {
  const long N1 = 221184L, N2 = 73728L, N3 = 98304L;  // 8-elem units
  const long total = N1 + N2 + N3;
  for (long i = (long)blockIdx.x * blockDim.x + threadIdx.x; i < total;
       i += (long)gridDim.x * blockDim.x) {
    if (i < N1 + N2) {
      const float* src; _Float16* dst; long off;
      if (i < N1) { src = wqkv;  dst = w16;  off = i; }
      else        { src = wproj; dst = wp16; off = i - N1; }
      const float4v* p = (const float4v*)(src + off * 8);
      float4v a = p[0], b = p[1];
      half8 o;
      o[0] = (_Float16)a[0]; o[1] = (_Float16)a[1]; o[2] = (_Float16)a[2]; o[3] = (_Float16)a[3];
      o[4] = (_Float16)b[0]; o[5] = (_Float16)b[1]; o[6] = (_Float16)b[2]; o[7] = (_Float16)b[3];
      *(half8*)(dst + off * 8) = o;
    } else {
      const long u = i - N1 - N2;
      const int h = (int)(u / 6144);
      const int r = (int)(u % 6144);
      const int f = r >> 3, e0 = (r & 7) * 8;
      half8 o;
      if (e0 >= 48) {
#pragma unroll
        for (int j = 0; j < 8; ++j) o[j] = (_Float16)0.f;
      } else {
#pragma unroll
        for (int j = 0; j < 8; ++j)
          o[j] = (_Float16)wqkv[(long)(1536 + h * 48 + e0 + j) * 768 + f];
      }
      *(half8*)(wvT + ((long)(h * 768 + f) * 64 + e0)) = o;
    }
  }
}

// ---------- x fp32 -> x16 [50176][768] AND xT [16][768][3136] ----------
__global__ __launch_bounds__(256)
void k_cvtx(const float* __restrict__ x, _Float16* __restrict__ x16,
            _Float16* __restrict__ xT) {
  __shared__ _Float16 lt[64 * 68];
  const int bid = blockIdx.x;
  const int b = bid / 588;
  const int rem = bid % 588;
  const int tt = rem / 12, ct = rem % 12;
  const long t0g = (long)b * 3136 + tt * 64;
  const int c0 = ct * 64;
  const int tid = threadIdx.x;
#pragma unroll
  for (int ch = 0; ch < 4; ++ch) {
    const int idx = tid + ch * 256;
    const int tr = idx >> 4, cg = (idx & 15) * 4;
    float4v v = *(const float4v*)&x[(t0g + tr) * 768 + c0 + cg];
    half4 hv;
    hv[0] = (_Float16)v[0]; hv[1] = (_Float16)v[1];
    hv[2] = (_Float16)v[2]; hv[3] = (_Float16)v[3];
    *(half4*)&x16[(t0g + tr) * 768 + c0 + cg] = hv;
    *(half4*)&lt[tr * 68 + cg] = hv;
  }
  __syncthreads();
  const int c = tid >> 2, tch = tid & 3;
  half8 o0, o1;
#pragma unroll
  for (int j = 0; j < 8; ++j) o0[j] = lt[(tch * 16 + j) * 68 + c];
#pragma unroll
  for (int j = 0; j < 8; ++j) o1[j] = lt[(tch * 16 + 8 + j) * 68 + c];
  _Float16* dst = xT + (long)b * 2408448 + (long)(c0 + c) * 3136 + tt * 64 + tch * 16;
  *(half8*)dst = o0;
  *(half8*)(dst + 8) = o1;
}

// ==================== Gram: G_b = xT_b . xT_b^T, symmetric 128^2 tiles ====================
__global__ __launch_bounds__(256)
void k_gram(const _Float16* __restrict__ xT, _Float16* __restrict__ G) {
  __shared__ _Float16 lds[2][2][128 * 32];
  const int tid = threadIdx.x;
  const int wv = tid >> 6, lane = tid & 63;
  const int g = lane >> 4, cidx = lane & 15;
  const int wr = wv >> 1, wc = wv & 1;

  const int nwg = (int)gridDim.x;
  const int q = nwg >> 3, r = nwg & 7;
  const int xcd = (int)blockIdx.x & 7, bidx = (int)blockIdx.x >> 3;
  int wg = (xcd < r ? xcd * (q + 1) : r * (q + 1) + (xcd - r) * q) + bidx;
  const int b = wg / 21;
  int p = wg % 21;
  int mt = 0;
  while (p >= 6 - mt) { p -= 6 - mt; ++mt; }
  const int nt = mt + p;

  const _Float16* Ab = xT + (long)b * 2408448 + (long)mt * 128 * 3136;
  const _Float16* Bb = xT + (long)b * 2408448 + (long)nt * 128 * 3136;

  const int srow = lane >> 2;
  const int sgr  = (lane & 3) ^ ((lane >> 3) & 3);

  auto stage = [&](int buf, int kt) {
#pragma unroll
    for (int l = 0; l < 2; ++l) {
      const int rbase = wv * 32 + l * 16;
      const long koff = (long)kt * 32 + sgr * 8;
      gload_lds16(Ab + (long)(rbase + srow) * 3136 + koff, &lds[buf][0][rbase * 32]);
      gload_lds16(Bb + (long)(rbase + srow) * 3136 + koff, &lds[buf][1][rbase * 32]);
    }
  };
  const int gr = (g ^ ((cidx >> 1) & 3)) * 8;

  f32x4 acc[4][4] = {};
  stage(0, 0);
  __syncthreads();
  for (int kt = 0; kt < 98; ++kt) {
    const int cur = kt & 1;
    if (kt + 1 < 98) stage(cur ^ 1, kt + 1);
    half8 af[4], bf[4];
#pragma unroll
    for (int m = 0; m < 4; ++m)
      af[m] = *(const half8*)&lds[cur][0][(wr * 64 + m * 16 + cidx) * 32 + gr];
#pragma unroll
    for (int n = 0; n < 4; ++n)
      bf[n] = *(const half8*)&lds[cur][1][(wc * 64 + n * 16 + cidx) * 32 + gr];
#pragma unroll
    for (int m = 0; m < 4; ++m)
#pragma unroll
      for (int n = 0; n < 4; ++n)
        acc[m][n] = MFMA_F16(af[m], bf[n], acc[m][n]);
    __syncthreads();
  }
  _Float16* Gb = G + (long)b * 589824;
  const long m0 = (long)mt * 128, n0 = (long)nt * 128;
#pragma unroll
  for (int m = 0; m < 4; ++m)
#pragma unroll
    for (int rr = 0; rr < 4; ++rr) {
      const long row = m0 + wr * 64 + m * 16 + g * 4 + rr;
#pragma unroll
      for (int n = 0; n < 4; ++n)
        Gb[row * 768 + n0 + wc * 64 + n * 16 + cidx] = (_Float16)acc[m][n][rr];
    }
  if (mt != nt) {
#pragma unroll
    for (int m = 0; m < 4; ++m)
#pragma unroll
      for (int n = 0; n < 4; ++n) {
        half4 hv;
#pragma unroll
        for (int rr = 0; rr < 4; ++rr) hv[rr] = (_Float16)acc[m][n][rr];
        const long col  = n0 + wc * 64 + n * 16 + cidx;
        const long row0 = m0 + wr * 64 + m * 16 + g * 4;
        *(half4*)&Gb[col * 768 + row0] = hv;
      }
  }
}

// ==================== generic batched 128^2 bt-GEMM (wfin) ====================
template<bool OUT_F32>
__global__ __launch_bounds__(256)
void k_g128(const _Float16* __restrict__ A, const _Float16* __restrict__ B,
            void* __restrict__ Cv, const float* __restrict__ bias,
            int Mt, int Nt, long Areal, long Astr, long Bstr, long Cstr,
            long N, long K)
{
  __shared__ _Float16 lds[2][2][128 * 32];
  const int tid = threadIdx.x;
  const int wv = tid >> 6, lane = tid & 63;
  const int g = lane >> 4, cidx = lane & 15;
  const int wr = wv >> 1, wc = wv & 1;

  const int nwg = (int)gridDim.x;
  const int q = nwg >> 3, r = nwg & 7;
  const int xcd = (int)blockIdx.x & 7, bidx = (int)blockIdx.x >> 3;
  int wg = (xcd < r ? xcd * (q + 1) : r * (q + 1) + (xcd - r) * q) + bidx;
  const int tpb = Mt * Nt;
  const int b = wg / tpb;
  const int rem = wg % tpb;
  const int mt = rem % Mt, nt = rem / Mt;
  const long m0 = (long)mt * 128, n0 = (long)nt * 128;

  const _Float16* Ab = A + b * Astr + m0 * K;
  const _Float16* Bb = B + b * Bstr + n0 * K;
  const int nkt = (int)(K >> 5);

  const int srow = lane >> 2;
  const int sgr  = (lane & 3) ^ ((lane >> 3) & 3);

  auto stage = [&](int buf, int kt) {
#pragma unroll
    for (int l = 0; l < 2; ++l) {
      const int rbase = wv * 32 + l * 16;
      const long koff = (long)kt * 32 + sgr * 8;
      gload_lds16(Ab + (long)(rbase + srow) * K + koff, &lds[buf][0][rbase * 32]);
      gload_lds16(Bb + (long)(rbase + srow) * K + koff, &lds[buf][1][rbase * 32]);
    }
  };
  const int gr = (g ^ ((cidx >> 1) & 3)) * 8;

  f32x4 acc[4][4] = {};
  stage(0, 0);
  __syncthreads();
  for (int kt = 0; kt < nkt; ++kt) {
    const int cur = kt & 1;
    if (kt + 1 < nkt) stage(cur ^ 1, kt + 1);
    half8 af[4], bf[4];
#pragma unroll
    for (int m = 0; m < 4; ++m)
      af[m] = *(const half8*)&lds[cur][0][(wr * 64 + m * 16 + cidx) * 32 + gr];
#pragma unroll
    for (int n = 0; n < 4; ++n)
      bf[n] = *(const half8*)&lds[cur][1][(wc * 64 + n * 16 + cidx) * 32 + gr];
#pragma unroll
    for (int m = 0; m < 4; ++m)
#pragma unroll
      for (int n = 0; n < 4; ++n)
        acc[m][n] = MFMA_F16(af[m], bf[n], acc[m][n]);
    __syncthreads();
  }

  float bv[4] = {0.f, 0.f, 0.f, 0.f};
  if (bias) {
#pragma unroll
    for (int n = 0; n < 4; ++n) bv[n] = bias[n0 + wc * 64 + n * 16 + cidx];
  }
  if constexpr (OUT_F32) {
    float* C = (float*)Cv + b * Cstr;
#pragma unroll
    for (int m = 0; m < 4; ++m)
#pragma unroll
      for (int rr = 0; rr < 4; ++rr) {
        const long row = m0 + wr * 64 + m * 16 + g * 4 + rr;
        if (row < Areal) {
#pragma unroll
          for (int n = 0; n < 4; ++n)
            C[row * N + n0 + wc * 64 + n * 16 + cidx] = acc[m][n][rr] + bv[n];
        }
      }
  } else {
    _Float16* C = (_Float16*)Cv + b * Cstr;
#pragma unroll
    for (int m = 0; m < 4; ++m)
#pragma unroll
      for (int rr = 0; rr < 4; ++rr) {
        const long row = m0 + wr * 64 + m * 16 + g * 4 + rr;
        if (row < Areal) {
#pragma unroll
          for (int n = 0; n < 4; ++n)
            C[row * N + n0 + wc * 64 + n * 16 + cidx] = (_Float16)acc[m][n][rr];
        }
      }
  }
}

// ==================== 256^2 2-phase bt-GEMM (final) ====================
// Same staging/swizzle geometry as verified R2 kernel; 8 waves (2M x 4N),
// per-wave 128x64, BK=32 double-buffered (64 KiB -> 2 blocks/CU).
template<bool OUT_F32>
__global__ __launch_bounds__(512, 2)
void k_g256(const _Float16* __restrict__ A, const _Float16* __restrict__ B,
            void* __restrict__ Cv, const float* __restrict__ bias,
            int Mt, int Nt, long Areal, long Astr, long Bstr, long Cstr,
            long N, long K)
{
  __shared__ _Float16 lds[2][2][256 * 32];  // 64 KiB
  const int tid = threadIdx.x;
  const int wv = tid >> 6, lane = tid & 63;
  const int g = lane >> 4, cidx = lane & 15;
  const int wr = wv >> 2, wc = wv & 3;

  const int nwg = (int)gridDim.x;
  const int q = nwg >> 3, r = nwg & 7;
  const int xcd = (int)blockIdx.x & 7, bidx = (int)blockIdx.x >> 3;
  int wg = (xcd < r ? xcd * (q + 1) : r * (q + 1) + (xcd - r) * q) + bidx;
  const int tpb = Mt * Nt;
  const int b = wg / tpb;
  const int rem = wg % tpb;
  const int mt = rem % Mt, nt = rem / Mt;
  const long m0 = (long)mt * 256, n0 = (long)nt * 256;

  const _Float16* Ab = A + b * Astr + m0 * K;
  const _Float16* Bb = B + b * Bstr + n0 * K;
  const int nkt = (int)(K >> 5);

  const int srow = lane >> 2;
  const int sgr  = (lane & 3) ^ ((lane >> 3) & 3);

  auto stage = [&](int buf, int kt) {
    const long koff = (long)kt * 32 + sgr * 8;
#pragma unroll
    for (int l = 0; l < 2; ++l) {
      const int chunk = l * 8 + wv;
      const long ro = (long)(chunk * 16 + srow);
      gload_lds16(Ab + ro * K + koff, &lds[buf][0][chunk * 512]);
      gload_lds16(Bb + ro * K + koff, &lds[buf][1][chunk * 512]);
    }
  };
  const int gr = (g ^ ((cidx >> 1) & 3)) * 8;

  f32x4 acc[8][4] = {};
  stage(0, 0);
  __syncthreads();
  for (int kt = 0; kt < nkt; ++kt) {
    const int cur = kt & 1;
    if (kt + 1 < nkt) stage(cur ^ 1, kt + 1);
    half8 af[8], bf[4];
#pragma unroll
    for (int m = 0; m < 8; ++m)
      af[m] = *(const half8*)&lds[cur][0][(wr * 128 + m * 16 + cidx) * 32 + gr];
#pragma unroll
    for (int n = 0; n < 4; ++n)
      bf[n] = *(const half8*)&lds[cur][1][(wc * 64 + n * 16 + cidx) * 32 + gr];
#pragma unroll
    for (int m = 0; m < 8; ++m)
#pragma unroll
      for (int n = 0; n < 4; ++n)
        acc[m][n] = MFMA_F16(af[m], bf[n], acc[m][n]);
    __syncthreads();
  }

  float bv[4] = {0.f, 0.f, 0.f, 0.f};
  if (bias) {
#pragma unroll
    for (int n = 0; n < 4; ++n) bv[n] = bias[n0 + wc * 64 + n * 16 + cidx];
  }
  if constexpr (OUT_F32) {
    float* C = (float*)Cv + b * Cstr;
#pragma unroll
    for (int m = 0; m < 8; ++m)
#pragma unroll
      for (int rr = 0; rr < 4; ++rr) {
        const long row = m0 + wr * 128 + m * 16 + g * 4 + rr;
        if (row < Areal) {
#pragma unroll
          for (int n = 0; n < 4; ++n)
            C[row * N + n0 + wc * 64 + n * 16 + cidx] = acc[m][n][rr] + bv[n];
        }
      }
  } else {
    _Float16* C = (_Float16*)Cv + b * Cstr;
#pragma unroll
    for (int m = 0; m < 8; ++m)
#pragma unroll
      for (int rr = 0; rr < 4; ++rr) {
        const long row = m0 + wr * 128 + m * 16 + g * 4 + rr;
        if (row < Areal) {
#pragma unroll
          for (int n = 0; n < 4; ++n)
            C[row * N + n0 + wc * 64 + n * 16 + cidx] = (_Float16)acc[m][n][rr];
        }
      }
  }
}

// ==================== heads2: T1/T3 from G + S/norms/softmax/WeffT ====================
// One block per (b,h), 512 thr = 8 waves, 1 block/CU (118 KiB LDS).
// T = Wa_h . G_b computed from L2 (G symmetric -> bt form). T stored in LDS with
// granule-XOR swizzle (c16-granule ^= d&7) to kill the stride-1536B A-frag conflict.
__global__ __launch_bounds__(512)
void k_heads2(const _Float16* __restrict__ G, const _Float16* __restrict__ w16,
              const _Float16* __restrict__ wvT, const float* __restrict__ temperature,
              _Float16* __restrict__ weffT)
{
  const int b = blockIdx.x >> 4, h = blockIdx.x & 15;
  const int tid = threadIdx.x;
  const int w = tid >> 6, lane = tid & 63;
  const int g = lane >> 4, c = lane & 15;

  __shared__ _Float16 T1s[48 * 768];     // 73,728 B (swizzled)
  __shared__ float red[4][48 * 48];      // 36,864 B
  __shared__ float redss[4][2][48];
  __shared__ float inv[2][48];
  __shared__ _Float16 Pb[48 * 64];

  const _Float16* Gb = G + (long)b * 589824;
  const _Float16* Wq = w16 + (long)(h * 48) * 768;
  const _Float16* Wk = w16 + (long)(768 + h * 48) * 768;

  for (int pass = 0; pass < 2; ++pass) {
    const _Float16* Wa = pass ? Wk : Wq;
    // ---- T = Wa . G  (M=48 -> 3 frags; N: wave w covers cols w*96..w*96+95) ----
    f32x4 accT[3][6] = {};
#pragma unroll 2
    for (int ks = 0; ks < 24; ++ks) {
      const int k0 = ks * 32 + g * 8;
      half8 a[3], bfr[6];
#pragma unroll
      for (int m = 0; m < 3; ++m)
        a[m] = *(const half8*)&Wa[(long)(m * 16 + c) * 768 + k0];
#pragma unroll
      for (int n = 0; n < 6; ++n)
        bfr[n] = *(const half8*)&Gb[(long)(w * 96 + n * 16 + c) * 768 + k0];
#pragma unroll
      for (int m = 0; m < 3; ++m)
#pragma unroll
        for (int n = 0; n < 6; ++n)
          accT[m][n] = MFMA_F16(a[m], bfr[n], accT[m][n]);
    }
    // write T to LDS (fp16, swizzled granules)
#pragma unroll
    for (int m = 0; m < 3; ++m)
#pragma unroll
      for (int n = 0; n < 6; ++n)
#pragma unroll
        for (int rr = 0; rr < 4; ++rr) {
          const int d = m * 16 + g * 4 + rr;
          const int col = w * 96 + n * 16 + c;
          const int u = d * 96 + ((col >> 3) ^ (d & 7));
          T1s[u * 8 + (col & 7)] = (_Float16)accT[m][n][rr];
        }
    __syncthreads();
    // ---- contraction (waves 0-3, k-split over 24 steps) ----
    if (w < 4) {
      if (pass == 0) {
        f32x4 aS[3][3] = {};
        f32x4 aq[3] = {};
        for (int ks = w * 6; ks < w * 6 + 6; ++ks) {
          const int k0 = ks * 32 + g * 8;
          const int cg = ks * 4 + g;
          half8 at[3], bk[3], bq[3];
#pragma unroll
          for (int m = 0; m < 3; ++m) {
            const int d = m * 16 + c;
            at[m] = *(const half8*)&T1s[(d * 96 + (cg ^ (d & 7))) * 8];
            bk[m] = *(const half8*)&Wk[(long)(m * 16 + c) * 768 + k0];
            bq[m] = *(const half8*)&Wq[(long)(m * 16 + c) * 768 + k0];
          }
#pragma unroll
          for (int m = 0; m < 3; ++m) {
            aq[m] = MFMA_F16(at[m], bq[m], aq[m]);
#pragma unroll
            for (int n = 0; n < 3; ++n)
              aS[m][n] = MFMA_F16(at[m], bk[n], aS[m][n]);
          }
        }
#pragma unroll
        for (int m = 0; m < 3; ++m) {
#pragma unroll
          for (int n = 0; n < 3; ++n)
#pragma unroll
            for (int rr = 0; rr < 4; ++rr)
              red[w][(m * 16 + g * 4 + rr) * 48 + n * 16 + c] = aS[m][n][rr];
#pragma unroll
          for (int rr = 0; rr < 4; ++rr)
            if (c == g * 4 + rr) redss[w][0][m * 16 + c] = aq[m][rr];
        }
      } else {
        f32x4 ak[3] = {};
        for (int ks = w * 6; ks < w * 6 + 6; ++ks) {
          const int k0 = ks * 32 + g * 8;
          const int cg = ks * 4 + g;
          half8 at[3], bk[3];
#pragma unroll
          for (int m = 0; m < 3; ++m) {
            const int d = m * 16 + c;
            at[m] = *(const half8*)&T1s[(d * 96 + (cg ^ (d & 7))) * 8];
            bk[m] = *(const half8*)&Wk[(long)(m * 16 + c) * 768 + k0];
          }
#pragma unroll
          for (int m = 0; m < 3; ++m)
            ak[m] = MFMA_F16(at[m], bk[m], ak[m]);
        }
#pragma unroll
        for (int m = 0; m < 3; ++m)
#pragma unroll
          for (int rr = 0; rr < 4; ++rr)
            if (c == g * 4 + rr) redss[w][1][m * 16 + c] = ak[m][rr];
      }
    }
    __syncthreads();
  }

  // ---- reduce + softmax ----
  if (tid < 96) {
    const int is_k = tid / 48, d = tid % 48;
    const float s = redss[0][is_k][d] + redss[1][is_k][d] + redss[2][is_k][d] + redss[3][is_k][d];
    inv[is_k][d] = 1.0f / fmaxf(sqrtf(s), 1e-12f);
  }
  __syncthreads();
  if (tid < 48) {
    const int d = tid;
    const float iq = inv[0][d] * temperature[h];
    float rowv[48];
    float mx = -3.0e38f;
#pragma unroll
    for (int e = 0; e < 48; ++e) {
      const int idx = d * 48 + e;
      float t = (red[0][idx] + red[1][idx] + red[2][idx] + red[3][idx]) * iq * inv[1][e];
      rowv[e] = t;
      mx = fmaxf(mx, t);
    }
    float sum = 0.f;
#pragma unroll
    for (int e = 0; e < 48; ++e) {
      const float pv = __expf(rowv[e] - mx);
      rowv[e] = pv;
      sum += pv;
    }
    const float is = 1.0f / sum;
#pragma unroll
    for (int e = 0; e < 48; ++e)
      Pb[d * 64 + e] = (_Float16)(rowv[e] * is);
#pragma unroll
    for (int e = 48; e < 64; ++e)
      Pb[d * 64 + e] = (_Float16)0.f;
  }
  __syncthreads();

  // ---- WeffT_b[f][h*48+d] = sum_e wvT[h][f][e] P[d][e]  (8 waves x 6 f-frags) ----
  half8 pf[3][2];
#pragma unroll
  for (int nf = 0; nf < 3; ++nf)
#pragma unroll
    for (int ks = 0; ks < 2; ++ks)
      pf[nf][ks] = *(const half8*)&Pb[(nf * 16 + c) * 64 + ks * 32 + g * 8];

  const _Float16* wvh = wvT + (long)h * 768 * 64;
  _Float16* wout = weffT + (long)b * 589824 + h * 48;

  for (int mi = 0; mi < 6; ++mi) {
    const int f0 = w * 96 + mi * 16;
    half8 va[2];
#pragma unroll
    for (int ks = 0; ks < 2; ++ks)
      va[ks] = *(const half8*)&wvh[(long)(f0 + c) * 64 + ks * 32 + g * 8];
    f32x4 a3[3] = {};
#pragma unroll
    for (int ks = 0; ks < 2; ++ks)
#pragma unroll
      for (int nf = 0; nf < 3; ++nf)
        a3[nf] = MFMA_F16(va[ks], pf[nf][ks], a3[nf]);
#pragma unroll
    for (int nf = 0; nf < 3; ++nf)
#pragma unroll
      for (int rr = 0; rr < 4; ++rr)
        wout[(long)(f0 + g * 4 + rr) * 768 + nf * 16 + c] = (_Float16)a3[nf][rr];
  }
}

// -------------------- launch --------------------
extern "C" void kernel_launch(void* const* d_in, const int* in_sizes, int n_in,
                              void* d_out, int out_size, void* d_ws, size_t ws_size,
                              hipStream_t stream)
{
  (void)in_sizes; (void)n_in; (void)out_size; (void)ws_size;
  const float* x      = (const float*)d_in[0];
  const float* w_qkv  = (const float*)d_in[1];
  const float* temp   = (const float*)d_in[2];
  const float* w_proj = (const float*)d_in[3];
  const float* b_proj = (const float*)d_in[4];
  float* out = (float*)d_out;

  // ws layout (bytes):
  //   [0)          x16   : 77,070,336   [50176][768]
  //   [77070336)   xT    : 77,070,336   [16][768][3136]
  //   [154140672)  G     : 18,874,368   [16][768][768]
  //   [210763776)  weffT : 18,874,368   [16][768 f][768 c]
  //   [229638144)  wfin  : 18,874,368   [16][768 o][768 f]
  //   [248512512)  w16   : 3,538,944
  //   [252051456)  wp16  : 1,179,648
  //   [253231104)  wvT   : 1,572,864
  char* ws = (char*)d_ws;
  _Float16* x16   = (_Float16*)(ws);
  _Float16* xT    = (_Float16*)(ws + 77070336L);
  _Float16* G     = (_Float16*)(ws + 154140672L);
  _Float16* weffT = (_Float16*)(ws + 210763776L);
  _Float16* wfin  = (_Float16*)(ws + 229638144L);
  _Float16* w16   = (_Float16*)(ws + 248512512L);
  _Float16* wp16  = (_Float16*)(ws + 252051456L);
  _Float16* wvT   = (_Float16*)(ws + 253231104L);

  k_cvtw<<<768, 256, 0, stream>>>(w_qkv, w_proj, w16, wp16, wvT);
  k_cvtx<<<9408, 256, 0, stream>>>(x, x16, xT);
  // G_b = xT_b . xT_b^T (symmetric)
  k_gram<<<336, 256, 0, stream>>>(xT, G);
  // per (b,h): T1/T3 from G, S, norms, softmax, WeffT
  k_heads2<<<256, 512, 0, stream>>>(G, w16, wvT, temp, weffT);
  // wfin_b = Wp . Weff_b
  k_g128<false><<<576, 256, 0, stream>>>(wp16, weffT, wfin, nullptr,
                                         6, 6, 768, 0, 589824, 589824, 768, 768);
  // out_b[t][o] = x16_b[t,:] . wfin_b[o,:] + bias  (fp32, M-tail masked)
  k_g256<true><<<624, 512, 0, stream>>>(x16, wfin, out, b_proj,
                                        13, 3, 3136, 3136L * 768, 589824, 3136L * 768,
                                        768, 768);
}

// Round 8
// 394.486 us; speedup vs baseline: 1.0371x; 1.0371x over previous
//
#include <hip/hip_runtime.h>
#include <hip/hip_bf16.h>
#include <stdint.h>

using f32x4   = __attribute__((ext_vector_type(4))) float;
using half8   = __attribute__((ext_vector_type(8))) _Float16;
using half4   = __attribute__((ext_vector_type(4))) _Float16;
using float4v = __attribute__((ext_vector_type(4))) float;

typedef const __attribute__((address_space(1))) void gas_void;
typedef __attribute__((address_space(3))) void las_void;

__device__ __forceinline__ void gload_lds16(const void* gptr, void* lptr) {
  __builtin_amdgcn_global_load_lds((gas_void*)(uintptr_t)gptr,
                                   (las_void*)(uintptr_t)lptr, 16, 0, 0);
}

#define MFMA_F16(a, b, c) __builtin_amdgcn_mfma_f32_16x16x32_f16((a), (b), (c), 0, 0, 0)

// ---------- weights fp32->fp16: w16 (2304x768), wp16, wvT (grid-stride) ----------
__global__ void k_cvtw(const float* __restrict__ wqkv, const float* __restrict__ wproj,
                       _Float16* __restrict__ w16, _Float16* __restrict__ wp16,
                       _Float16* __restrict__ wvT) {
  const long N1 = 221184L, N2 = 73728L, N3 = 98304L;  // 8-elem units
  const long total = N1 + N2 + N3;
  for (long i = (long)blockIdx.x * blockDim.x + threadIdx.x; i < total;
       i += (long)gridDim.x * blockDim.x) {
    if (i < N1 + N2) {
      const float* src; _Float16* dst; long off;
      if (i < N1) { src = wqkv;  dst = w16;  off = i; }
      else        { src = wproj; dst = wp16; off = i - N1; }
      const float4v* p = (const float4v*)(src + off * 8);
      float4v a = p[0], b = p[1];
      half8 o;
      o[0] = (_Float16)a[0]; o[1] = (_Float16)a[1]; o[2] = (_Float16)a[2]; o[3] = (_Float16)a[3];
      o[4] = (_Float16)b[0]; o[5] = (_Float16)b[1]; o[6] = (_Float16)b[2]; o[7] = (_Float16)b[3];
      *(half8*)(dst + off * 8) = o;
    } else {
      const long u = i - N1 - N2;
      const int h = (int)(u / 6144);
      const int r = (int)(u % 6144);
      const int f = r >> 3, e0 = (r & 7) * 8;
      half8 o;
      if (e0 >= 48) {
#pragma unroll
        for (int j = 0; j < 8; ++j) o[j] = (_Float16)0.f;
      } else {
#pragma unroll
        for (int j = 0; j < 8; ++j)
          o[j] = (_Float16)wqkv[(long)(1536 + h * 48 + e0 + j) * 768 + f];
      }
      *(half8*)(wvT + ((long)(h * 768 + f) * 64 + e0)) = o;
    }
  }
}

// ---------- x fp32 -> x16 [50176][768] AND xT [16][768][3136] ----------
__global__ __launch_bounds__(256)
void k_cvtx(const float* __restrict__ x, _Float16* __restrict__ x16,
            _Float16* __restrict__ xT) {
  __shared__ _Float16 lt[64 * 68];
  const int bid = blockIdx.x;
  const int b = bid / 588;
  const int rem = bid % 588;
  const int tt = rem / 12, ct = rem % 12;
  const long t0g = (long)b * 3136 + tt * 64;
  const int c0 = ct * 64;
  const int tid = threadIdx.x;
#pragma unroll
  for (int ch = 0; ch < 4; ++ch) {
    const int idx = tid + ch * 256;
    const int tr = idx >> 4, cg = (idx & 15) * 4;
    float4v v = *(const float4v*)&x[(t0g + tr) * 768 + c0 + cg];
    half4 hv;
    hv[0] = (_Float16)v[0]; hv[1] = (_Float16)v[1];
    hv[2] = (_Float16)v[2]; hv[3] = (_Float16)v[3];
    *(half4*)&x16[(t0g + tr) * 768 + c0 + cg] = hv;
    *(half4*)&lt[tr * 68 + cg] = hv;
  }
  __syncthreads();
  const int c = tid >> 2, tch = tid & 3;
  half8 o0, o1;
#pragma unroll
  for (int j = 0; j < 8; ++j) o0[j] = lt[(tch * 16 + j) * 68 + c];
#pragma unroll
  for (int j = 0; j < 8; ++j) o1[j] = lt[(tch * 16 + 8 + j) * 68 + c];
  _Float16* dst = xT + (long)b * 2408448 + (long)(c0 + c) * 3136 + tt * 64 + tch * 16;
  *(half8*)dst = o0;
  *(half8*)(dst + 8) = o1;
}

// ==================== Gram: G_b = xT_b . xT_b^T, symmetric 128^2 tiles ====================
__global__ __launch_bounds__(256)
void k_gram(const _Float16* __restrict__ xT, _Float16* __restrict__ G) {
  __shared__ _Float16 lds[2][2][128 * 32];
  const int tid = threadIdx.x;
  const int wv = tid >> 6, lane = tid & 63;
  const int g = lane >> 4, cidx = lane & 15;
  const int wr = wv >> 1, wc = wv & 1;

  const int nwg = (int)gridDim.x;
  const int q = nwg >> 3, r = nwg & 7;
  const int xcd = (int)blockIdx.x & 7, bidx = (int)blockIdx.x >> 3;
  int wg = (xcd < r ? xcd * (q + 1) : r * (q + 1) + (xcd - r) * q) + bidx;
  const int b = wg / 21;
  int p = wg % 21;
  int mt = 0;
  while (p >= 6 - mt) { p -= 6 - mt; ++mt; }
  const int nt = mt + p;

  const _Float16* Ab = xT + (long)b * 2408448 + (long)mt * 128 * 3136;
  const _Float16* Bb = xT + (long)b * 2408448 + (long)nt * 128 * 3136;

  const int srow = lane >> 2;
  const int sgr  = (lane & 3) ^ ((lane >> 3) & 3);

  auto stage = [&](int buf, int kt) {
#pragma unroll
    for (int l = 0; l < 2; ++l) {
      const int rbase = wv * 32 + l * 16;
      const long koff = (long)kt * 32 + sgr * 8;
      gload_lds16(Ab + (long)(rbase + srow) * 3136 + koff, &lds[buf][0][rbase * 32]);
      gload_lds16(Bb + (long)(rbase + srow) * 3136 + koff, &lds[buf][1][rbase * 32]);
    }
  };
  const int gr = (g ^ ((cidx >> 1) & 3)) * 8;

  f32x4 acc[4][4] = {};
  stage(0, 0);
  __syncthreads();
  for (int kt = 0; kt < 98; ++kt) {
    const int cur = kt & 1;
    if (kt + 1 < 98) stage(cur ^ 1, kt + 1);
    half8 af[4], bf[4];
#pragma unroll
    for (int m = 0; m < 4; ++m)
      af[m] = *(const half8*)&lds[cur][0][(wr * 64 + m * 16 + cidx) * 32 + gr];
#pragma unroll
    for (int n = 0; n < 4; ++n)
      bf[n] = *(const half8*)&lds[cur][1][(wc * 64 + n * 16 + cidx) * 32 + gr];
#pragma unroll
    for (int m = 0; m < 4; ++m)
#pragma unroll
      for (int n = 0; n < 4; ++n)
        acc[m][n] = MFMA_F16(af[m], bf[n], acc[m][n]);
    __syncthreads();
  }
  _Float16* Gb = G + (long)b * 589824;
  const long m0 = (long)mt * 128, n0 = (long)nt * 128;
#pragma unroll
  for (int m = 0; m < 4; ++m)
#pragma unroll
    for (int rr = 0; rr < 4; ++rr) {
      const long row = m0 + wr * 64 + m * 16 + g * 4 + rr;
#pragma unroll
      for (int n = 0; n < 4; ++n)
        Gb[row * 768 + n0 + wc * 64 + n * 16 + cidx] = (_Float16)acc[m][n][rr];
    }
  if (mt != nt) {
#pragma unroll
    for (int m = 0; m < 4; ++m)
#pragma unroll
      for (int n = 0; n < 4; ++n) {
        half4 hv;
#pragma unroll
        for (int rr = 0; rr < 4; ++rr) hv[rr] = (_Float16)acc[m][n][rr];
        const long col  = n0 + wc * 64 + n * 16 + cidx;
        const long row0 = m0 + wr * 64 + m * 16 + g * 4;
        *(half4*)&Gb[col * 768 + row0] = hv;
      }
  }
}

// ==================== generic batched 128^2 bt-GEMM (wfin) ====================
template<bool OUT_F32>
__global__ __launch_bounds__(256)
void k_g128(const _Float16* __restrict__ A, const _Float16* __restrict__ B,
            void* __restrict__ Cv, const float* __restrict__ bias,
            int Mt, int Nt, long Areal, long Astr, long Bstr, long Cstr,
            long N, long K)
{
  __shared__ _Float16 lds[2][2][128 * 32];
  const int tid = threadIdx.x;
  const int wv = tid >> 6, lane = tid & 63;
  const int g = lane >> 4, cidx = lane & 15;
  const int wr = wv >> 1, wc = wv & 1;

  const int nwg = (int)gridDim.x;
  const int q = nwg >> 3, r = nwg & 7;
  const int xcd = (int)blockIdx.x & 7, bidx = (int)blockIdx.x >> 3;
  int wg = (xcd < r ? xcd * (q + 1) : r * (q + 1) + (xcd - r) * q) + bidx;
  const int tpb = Mt * Nt;
  const int b = wg / tpb;
  const int rem = wg % tpb;
  const int mt = rem % Mt, nt = rem / Mt;
  const long m0 = (long)mt * 128, n0 = (long)nt * 128;

  const _Float16* Ab = A + b * Astr + m0 * K;
  const _Float16* Bb = B + b * Bstr + n0 * K;
  const int nkt = (int)(K >> 5);

  const int srow = lane >> 2;
  const int sgr  = (lane & 3) ^ ((lane >> 3) & 3);

  auto stage = [&](int buf, int kt) {
#pragma unroll
    for (int l = 0; l < 2; ++l) {
      const int rbase = wv * 32 + l * 16;
      const long koff = (long)kt * 32 + sgr * 8;
      gload_lds16(Ab + (long)(rbase + srow) * K + koff, &lds[buf][0][rbase * 32]);
      gload_lds16(Bb + (long)(rbase + srow) * K + koff, &lds[buf][1][rbase * 32]);
    }
  };
  const int gr = (g ^ ((cidx >> 1) & 3)) * 8;

  f32x4 acc[4][4] = {};
  stage(0, 0);
  __syncthreads();
  for (int kt = 0; kt < nkt; ++kt) {
    const int cur = kt & 1;
    if (kt + 1 < nkt) stage(cur ^ 1, kt + 1);
    half8 af[4], bf[4];
#pragma unroll
    for (int m = 0; m < 4; ++m)
      af[m] = *(const half8*)&lds[cur][0][(wr * 64 + m * 16 + cidx) * 32 + gr];
#pragma unroll
    for (int n = 0; n < 4; ++n)
      bf[n] = *(const half8*)&lds[cur][1][(wc * 64 + n * 16 + cidx) * 32 + gr];
#pragma unroll
    for (int m = 0; m < 4; ++m)
#pragma unroll
      for (int n = 0; n < 4; ++n)
        acc[m][n] = MFMA_F16(af[m], bf[n], acc[m][n]);
    __syncthreads();
  }

  float bv[4] = {0.f, 0.f, 0.f, 0.f};
  if (bias) {
#pragma unroll
    for (int n = 0; n < 4; ++n) bv[n] = bias[n0 + wc * 64 + n * 16 + cidx];
  }
  if constexpr (OUT_F32) {
    float* C = (float*)Cv + b * Cstr;
#pragma unroll
    for (int m = 0; m < 4; ++m)
#pragma unroll
      for (int rr = 0; rr < 4; ++rr) {
        const long row = m0 + wr * 64 + m * 16 + g * 4 + rr;
        if (row < Areal) {
#pragma unroll
          for (int n = 0; n < 4; ++n)
            C[row * N + n0 + wc * 64 + n * 16 + cidx] = acc[m][n][rr] + bv[n];
        }
      }
  } else {
    _Float16* C = (_Float16*)Cv + b * Cstr;
#pragma unroll
    for (int m = 0; m < 4; ++m)
#pragma unroll
      for (int rr = 0; rr < 4; ++rr) {
        const long row = m0 + wr * 64 + m * 16 + g * 4 + rr;
        if (row < Areal) {
#pragma unroll
          for (int n = 0; n < 4; ++n)
            C[row * N + n0 + wc * 64 + n * 16 + cidx] = (_Float16)acc[m][n][rr];
        }
      }
  }
}

// ==================== 256x256 8-phase bt-GEMM, batched + M-tail mask (R5-verified) ====================
template<bool OUT_F32>
__global__ __launch_bounds__(512, 2)
void k_gemm8p(const _Float16* __restrict__ A, const _Float16* __restrict__ B,
              void* __restrict__ Cv, const float* __restrict__ bias,
              int Mt, int Nt, long Areal, long Astr, long Bstr, long Cstr,
              long N, long K)
{
  __shared__ _Float16 lds[65536];  // 128 KiB
  const int tid  = threadIdx.x;
  const int wv   = tid >> 6, lane = tid & 63;
  const int g    = lane >> 4, cidx = lane & 15;
  const int wr   = wv >> 2, wc = wv & 3;

  const int nwg = (int)gridDim.x;
  const int q = nwg >> 3, r = nwg & 7;
  const int xcd = (int)blockIdx.x & 7, bidx = (int)blockIdx.x >> 3;
  int wg = (xcd < r ? xcd * (q + 1) : r * (q + 1) + (xcd - r) * q) + bidx;

  const int tpb = Mt * Nt;
  const int b   = wg / tpb;
  const int rem = wg - b * tpb;
  const long mt = rem % Mt, nt = rem / Mt;
  const long m0 = mt * 256, n0 = nt * 256;

  const int NT = (int)(K >> 6);
  const int NI = NT >> 1;

  const _Float16* Ab = A + b * Astr + m0 * K;
  const _Float16* Bb = B + b * Bstr + n0 * K;

  const int srow = lane >> 2;
  const int sgr  = (lane & 3) ^ ((lane >> 3) & 3);

  auto stage = [&](int op, int buf, int kh, int t) {
    const _Float16* src = op ? Bb : Ab;
    const long koff = (long)t * 64 + kh * 32 + sgr * 8;
#pragma unroll
    for (int l = 0; l < 2; ++l) {
      const int chunk = l * 8 + wv;
      gload_lds16(src + (long)(chunk * 16 + srow) * K + koff,
                  &lds[buf * 32768 + op * 16384 + kh * 8192 + chunk * 512]);
    }
  };

  const int gr  = (g ^ ((cidx >> 1) & 3)) * 8;
  const int raA = (wr * 128 + cidx) * 32 + gr;
  const int raB = 16384 + (wc * 64 + cidx) * 32 + gr;

  f32x4 acc[8][4] = {};

  stage(0, 0, 0, 0); stage(1, 0, 0, 0);
  stage(0, 0, 1, 0); stage(1, 0, 1, 0);
  stage(0, 1, 0, 1); stage(1, 1, 0, 1);
  asm volatile("s_waitcnt vmcnt(4)" ::: "memory");
  __builtin_amdgcn_sched_barrier(0);
  __builtin_amdgcn_s_barrier();

  half8 afA[4], afB[4], bfA[4], bfB[4];
#pragma unroll
  for (int mm = 0; mm < 4; ++mm) afA[mm] = *(const half8*)&lds[raA + mm * 512];
#pragma unroll
  for (int nn = 0; nn < 4; ++nn) bfA[nn] = *(const half8*)&lds[raB + nn * 512];

#define XPH(CURA, CURB, MLO, NA, NBUF, NKS, NMLO, LOADB, NB, STAGE, BDRY)      \
  {                                                                            \
    STAGE;                                                                     \
    if (BDRY) {                                                                \
      asm volatile("s_waitcnt vmcnt(4)" ::: "memory");                         \
      __builtin_amdgcn_sched_barrier(0);                                       \
    }                                                                          \
    __builtin_amdgcn_s_barrier();                                              \
    _Pragma("unroll")                                                          \
    for (int mm = 0; mm < 4; ++mm)                                             \
      NA[mm] = *(const half8*)&lds[(NBUF)*32768 + (NKS)*8192 + raA + ((NMLO)+mm)*512]; \
    if (LOADB) {                                                               \
      _Pragma("unroll")                                                        \
      for (int nn = 0; nn < 4; ++nn)                                           \
        NB[nn] = *(const half8*)&lds[(NBUF)*32768 + (NKS)*8192 + raB + nn*512]; \
    }                                                                          \
    __builtin_amdgcn_sched_barrier(0);                                         \
    __builtin_amdgcn_s_setprio(1);                                             \
    _Pragma("unroll")                                                          \
    for (int mm = 0; mm < 4; ++mm)                                             \
      _Pragma("unroll")                                                        \
      for (int nn = 0; nn < 4; ++nn)                                           \
        acc[(MLO)+mm][nn] = MFMA_F16(CURA[mm], CURB[nn], acc[(MLO)+mm][nn]);   \
    __builtin_amdgcn_s_setprio(0);                                             \
    __builtin_amdgcn_s_barrier();                                              \
  }

  for (int it = 0; it < NI; ++it) {
    const int t1c = 2 * it + 1;
    int tn2 = 2 * it + 2; if (tn2 >= NT) tn2 -= NT;
    int tn3 = 2 * it + 3; if (tn3 >= NT) tn3 -= NT;
    XPH(afA, bfA, 0, afB, 0, 0, 4, 0, bfB, stage(0, 1, 1, t1c), false)
    XPH(afB, bfA, 4, afA, 0, 1, 0, 1, bfB, stage(1, 1, 1, t1c), false)
    XPH(afA, bfB, 0, afB, 0, 1, 4, 0, bfA, stage(0, 0, 0, tn2), false)
    XPH(afB, bfB, 4, afA, 1, 0, 0, 1, bfA, stage(1, 0, 0, tn2), true )
    XPH(afA, bfA, 0, afB, 1, 0, 4, 0, bfB, stage(0, 0, 1, tn2), false)
    XPH(afB, bfA, 4, afA, 1, 1, 0, 1, bfB, stage(1, 0, 1, tn2), false)
    XPH(afA, bfB, 0, afB, 1, 1, 4, 0, bfA, stage(0, 1, 0, tn3), false)
    XPH(afB, bfB, 4, afA, 0, 0, 0, 1, bfA, stage(1, 1, 0, tn3), true )
  }
#undef XPH

  float bv[4] = {0.f, 0.f, 0.f, 0.f};
  if (bias) {
#pragma unroll
    for (int n = 0; n < 4; ++n) bv[n] = bias[n0 + wc * 64 + n * 16 + cidx];
  }
  if constexpr (OUT_F32) {
    float* C = (float*)Cv + b * Cstr;
#pragma unroll
    for (int m = 0; m < 8; ++m)
#pragma unroll
      for (int rr = 0; rr < 4; ++rr) {
        const long row = m0 + wr * 128 + m * 16 + g * 4 + rr;
        if (row < Areal) {
#pragma unroll
          for (int n = 0; n < 4; ++n)
            C[row * N + (n0 + wc * 64 + n * 16 + cidx)] = acc[m][n][rr] + bv[n];
        }
      }
  } else {
    _Float16* C = (_Float16*)Cv + b * Cstr;
#pragma unroll
    for (int m = 0; m < 8; ++m)
#pragma unroll
      for (int rr = 0; rr < 4; ++rr) {
        const long row = m0 + wr * 128 + m * 16 + g * 4 + rr;
        if (row < Areal) {
#pragma unroll
          for (int n = 0; n < 4; ++n)
            C[row * N + (n0 + wc * 64 + n * 16 + cidx)] = (_Float16)acc[m][n][rr];
        }
      }
  }
}

// ==================== heads2: T1/T3 from G + S/norms/softmax/WeffT ====================
// One block per (b,h), 512 thr = 8 waves, 1 block/CU (118 KiB LDS).
// Block index mapped so ALL 16 h-blocks of batch b land on XCD b%8 (hardware
// XCD = blockIdx % 8): per-XCD working set = 2 G_b = 2.4 MB < 4 MB L2.
__global__ __launch_bounds__(512)
void k_heads2(const _Float16* __restrict__ G, const _Float16* __restrict__ w16,
              const _Float16* __restrict__ wvT, const float* __restrict__ temperature,
              _Float16* __restrict__ weffT)
{
  const int i = (int)blockIdx.x;
  const int b = (i & 7) + ((i >> 7) << 3);   // XCD(i)=i%8 == b%8
  const int h = (i >> 3) & 15;
  const int tid = threadIdx.x;
  const int w = tid >> 6, lane = tid & 63;
  const int g = lane >> 4, c = lane & 15;

  __shared__ _Float16 T1s[48 * 768];
  __shared__ float red[4][48 * 48];
  __shared__ float redss[4][2][48];
  __shared__ float inv[2][48];
  __shared__ _Float16 Pb[48 * 64];

  const _Float16* Gb = G + (long)b * 589824;
  const _Float16* Wq = w16 + (long)(h * 48) * 768;
  const _Float16* Wk = w16 + (long)(768 + h * 48) * 768;

  for (int pass = 0; pass < 2; ++pass) {
    const _Float16* Wa = pass ? Wk : Wq;
    f32x4 accT[3][6] = {};
#pragma unroll 2
    for (int ks = 0; ks < 24; ++ks) {
      const int k0 = ks * 32 + g * 8;
      half8 a[3], bfr[6];
#pragma unroll
      for (int m = 0; m < 3; ++m)
        a[m] = *(const half8*)&Wa[(long)(m * 16 + c) * 768 + k0];
#pragma unroll
      for (int n = 0; n < 6; ++n)
        bfr[n] = *(const half8*)&Gb[(long)(w * 96 + n * 16 + c) * 768 + k0];
#pragma unroll
      for (int m = 0; m < 3; ++m)
#pragma unroll
        for (int n = 0; n < 6; ++n)
          accT[m][n] = MFMA_F16(a[m], bfr[n], accT[m][n]);
    }
#pragma unroll
    for (int m = 0; m < 3; ++m)
#pragma unroll
      for (int n = 0; n < 6; ++n)
#pragma unroll
        for (int rr = 0; rr < 4; ++rr) {
          const int d = m * 16 + g * 4 + rr;
          const int col = w * 96 + n * 16 + c;
          const int u = d * 96 + ((col >> 3) ^ (d & 7));
          T1s[u * 8 + (col & 7)] = (_Float16)accT[m][n][rr];
        }
    __syncthreads();
    if (w < 4) {
      if (pass == 0) {
        f32x4 aS[3][3] = {};
        f32x4 aq[3] = {};
        for (int ks = w * 6; ks < w * 6 + 6; ++ks) {
          const int k0 = ks * 32 + g * 8;
          const int cg = ks * 4 + g;
          half8 at[3], bk[3], bq[3];
#pragma unroll
          for (int m = 0; m < 3; ++m) {
            const int d = m * 16 + c;
            at[m] = *(const half8*)&T1s[(d * 96 + (cg ^ (d & 7))) * 8];
            bk[m] = *(const half8*)&Wk[(long)(m * 16 + c) * 768 + k0];
            bq[m] = *(const half8*)&Wq[(long)(m * 16 + c) * 768 + k0];
          }
#pragma unroll
          for (int m = 0; m < 3; ++m) {
            aq[m] = MFMA_F16(at[m], bq[m], aq[m]);
#pragma unroll
            for (int n = 0; n < 3; ++n)
              aS[m][n] = MFMA_F16(at[m], bk[n], aS[m][n]);
          }
        }
#pragma unroll
        for (int m = 0; m < 3; ++m) {
#pragma unroll
          for (int n = 0; n < 3; ++n)
#pragma unroll
            for (int rr = 0; rr < 4; ++rr)
              red[w][(m * 16 + g * 4 + rr) * 48 + n * 16 + c] = aS[m][n][rr];
#pragma unroll
          for (int rr = 0; rr < 4; ++rr)
            if (c == g * 4 + rr) redss[w][0][m * 16 + c] = aq[m][rr];
        }
      } else {
        f32x4 ak[3] = {};
        for (int ks = w * 6; ks < w * 6 + 6; ++ks) {
          const int k0 = ks * 32 + g * 8;
          const int cg = ks * 4 + g;
          half8 at[3], bk[3];
#pragma unroll
          for (int m = 0; m < 3; ++m) {
            const int d = m * 16 + c;
            at[m] = *(const half8*)&T1s[(d * 96 + (cg ^ (d & 7))) * 8];
            bk[m] = *(const half8*)&Wk[(long)(m * 16 + c) * 768 + k0];
          }
#pragma unroll
          for (int m = 0; m < 3; ++m)
            ak[m] = MFMA_F16(at[m], bk[m], ak[m]);
        }
#pragma unroll
        for (int m = 0; m < 3; ++m)
#pragma unroll
          for (int rr = 0; rr < 4; ++rr)
            if (c == g * 4 + rr) redss[w][1][m * 16 + c] = ak[m][rr];
      }
    }
    __syncthreads();
  }

  if (tid < 96) {
    const int is_k = tid / 48, d = tid % 48;
    const float s = redss[0][is_k][d] + redss[1][is_k][d] + redss[2][is_k][d] + redss[3][is_k][d];
    inv[is_k][d] = 1.0f / fmaxf(sqrtf(s), 1e-12f);
  }
  __syncthreads();
  if (tid < 48) {
    const int d = tid;
    const float iq = inv[0][d] * temperature[h];
    float rowv[48];
    float mx = -3.0e38f;
#pragma unroll
    for (int e = 0; e < 48; ++e) {
      const int idx = d * 48 + e;
      float t = (red[0][idx] + red[1][idx] + red[2][idx] + red[3][idx]) * iq * inv[1][e];
      rowv[e] = t;
      mx = fmaxf(mx, t);
    }
    float sum = 0.f;
#pragma unroll
    for (int e = 0; e < 48; ++e) {
      const float pv = __expf(rowv[e] - mx);
      rowv[e] = pv;
      sum += pv;
    }
    const float is = 1.0f / sum;
#pragma unroll
    for (int e = 0; e < 48; ++e)
      Pb[d * 64 + e] = (_Float16)(rowv[e] * is);
#pragma unroll
    for (int e = 48; e < 64; ++e)
      Pb[d * 64 + e] = (_Float16)0.f;
  }
  __syncthreads();

  half8 pf[3][2];
#pragma unroll
  for (int nf = 0; nf < 3; ++nf)
#pragma unroll
    for (int ks = 0; ks < 2; ++ks)
      pf[nf][ks] = *(const half8*)&Pb[(nf * 16 + c) * 64 + ks * 32 + g * 8];

  const _Float16* wvh = wvT + (long)h * 768 * 64;
  _Float16* wout = weffT + (long)b * 589824 + h * 48;

  for (int mi = 0; mi < 6; ++mi) {
    const int f0 = w * 96 + mi * 16;
    half8 va[2];
#pragma unroll
    for (int ks = 0; ks < 2; ++ks)
      va[ks] = *(const half8*)&wvh[(long)(f0 + c) * 64 + ks * 32 + g * 8];
    f32x4 a3[3] = {};
#pragma unroll
    for (int ks = 0; ks < 2; ++ks)
#pragma unroll
      for (int nf = 0; nf < 3; ++nf)
        a3[nf] = MFMA_F16(va[ks], pf[nf][ks], a3[nf]);
#pragma unroll
    for (int nf = 0; nf < 3; ++nf)
#pragma unroll
      for (int rr = 0; rr < 4; ++rr)
        wout[(long)(f0 + g * 4 + rr) * 768 + nf * 16 + c] = (_Float16)a3[nf][rr];
  }
}

// -------------------- launch --------------------
extern "C" void kernel_launch(void* const* d_in, const int* in_sizes, int n_in,
                              void* d_out, int out_size, void* d_ws, size_t ws_size,
                              hipStream_t stream)
{
  (void)in_sizes; (void)n_in; (void)out_size; (void)ws_size;
  const float* x      = (const float*)d_in[0];
  const float* w_qkv  = (const float*)d_in[1];
  const float* temp   = (const float*)d_in[2];
  const float* w_proj = (const float*)d_in[3];
  const float* b_proj = (const float*)d_in[4];
  float* out = (float*)d_out;

  char* ws = (char*)d_ws;
  _Float16* x16   = (_Float16*)(ws);
  _Float16* xT    = (_Float16*)(ws + 77070336L);
  _Float16* G     = (_Float16*)(ws + 154140672L);
  _Float16* weffT = (_Float16*)(ws + 210763776L);
  _Float16* wfin  = (_Float16*)(ws + 229638144L);
  _Float16* w16   = (_Float16*)(ws + 248512512L);
  _Float16* wp16  = (_Float16*)(ws + 252051456L);
  _Float16* wvT   = (_Float16*)(ws + 253231104L);

  k_cvtw<<<768, 256, 0, stream>>>(w_qkv, w_proj, w16, wp16, wvT);
  k_cvtx<<<9408, 256, 0, stream>>>(x, x16, xT);
  // G_b = xT_b . xT_b^T (symmetric)
  k_gram<<<336, 256, 0, stream>>>(xT, G);
  // per (b,h): T1/T3 from G, S, norms, softmax, WeffT  (XCD-pinned per batch)
  k_heads2<<<256, 512, 0, stream>>>(G, w16, wvT, temp, weffT);
  // wfin_b = Wp . Weff_b
  k_g128<false><<<576, 256, 0, stream>>>(wp16, weffT, wfin, nullptr,
                                         6, 6, 768, 0, 589824, 589824, 768, 768);
  // out_b[t][o] = x16_b[t,:] . wfin_b[o,:] + bias  (fp32, 8-phase, M-tail masked)
  k_gemm8p<true><<<624, 512, 0, stream>>>(x16, wfin, out, b_proj,
                                          13, 3, 3136, 3136L * 768, 589824, 3136L * 768,
                                          768, 768);
}

// Round 9
// 338.950 us; speedup vs baseline: 1.2071x; 1.1638x over previous
//
#include <hip/hip_runtime.h>
#include <hip/hip_bf16.h>
#include <stdint.h>

using f32x4   = __attribute__((ext_vector_type(4))) float;
using half8   = __attribute__((ext_vector_type(8))) _Float16;
using half4   = __attribute__((ext_vector_type(4))) _Float16;
using float4v = __attribute__((ext_vector_type(4))) float;

typedef const __attribute__((address_space(1))) void gas_void;
typedef __attribute__((address_space(3))) void las_void;

__device__ __forceinline__ void gload_lds16(const void* gptr, void* lptr) {
  __builtin_amdgcn_global_load_lds((gas_void*)(uintptr_t)gptr,
                                   (las_void*)(uintptr_t)lptr, 16, 0, 0);
}

#define MFMA_F16(a, b, c) __builtin_amdgcn_mfma_f32_16x16x32_f16((a), (b), (c), 0, 0, 0)

// ---------- weights fp32->fp16: w16 (2304x768), wp16, wvT (grid-stride) ----------
__global__ void k_cvtw(const float* __restrict__ wqkv, const float* __restrict__ wproj,
                       _Float16* __restrict__ w16, _Float16* __restrict__ wp16,
                       _Float16* __restrict__ wvT) {
  const long N1 = 221184L, N2 = 73728L, N3 = 98304L;  // 8-elem units
  const long total = N1 + N2 + N3;
  for (long i = (long)blockIdx.x * blockDim.x + threadIdx.x; i < total;
       i += (long)gridDim.x * blockDim.x) {
    if (i < N1 + N2) {
      const float* src; _Float16* dst; long off;
      if (i < N1) { src = wqkv;  dst = w16;  off = i; }
      else        { src = wproj; dst = wp16; off = i - N1; }
      const float4v* p = (const float4v*)(src + off * 8);
      float4v a = p[0], b = p[1];
      half8 o;
      o[0] = (_Float16)a[0]; o[1] = (_Float16)a[1]; o[2] = (_Float16)a[2]; o[3] = (_Float16)a[3];
      o[4] = (_Float16)b[0]; o[5] = (_Float16)b[1]; o[6] = (_Float16)b[2]; o[7] = (_Float16)b[3];
      *(half8*)(dst + off * 8) = o;
    } else {
      const long u = i - N1 - N2;
      const int h = (int)(u / 6144);
      const int r = (int)(u % 6144);
      const int f = r >> 3, e0 = (r & 7) * 8;
      half8 o;
      if (e0 >= 48) {
#pragma unroll
        for (int j = 0; j < 8; ++j) o[j] = (_Float16)0.f;
      } else {
#pragma unroll
        for (int j = 0; j < 8; ++j)
          o[j] = (_Float16)wqkv[(long)(1536 + h * 48 + e0 + j) * 768 + f];
      }
      *(half8*)(wvT + ((long)(h * 768 + f) * 64 + e0)) = o;
    }
  }
}

// ---------- x fp32 -> x16 [50176][768] AND xT [16][768][3136] ----------
__global__ __launch_bounds__(256)
void k_cvtx(const float* __restrict__ x, _Float16* __restrict__ x16,
            _Float16* __restrict__ xT) {
  __shared__ _Float16 lt[64 * 68];
  const int bid = blockIdx.x;
  const int b = bid / 588;
  const int rem = bid % 588;
  const int tt = rem / 12, ct = rem % 12;
  const long t0g = (long)b * 3136 + tt * 64;
  const int c0 = ct * 64;
  const int tid = threadIdx.x;
#pragma unroll
  for (int ch = 0; ch < 4; ++ch) {
    const int idx = tid + ch * 256;
    const int tr = idx >> 4, cg = (idx & 15) * 4;
    float4v v = *(const float4v*)&x[(t0g + tr) * 768 + c0 + cg];
    half4 hv;
    hv[0] = (_Float16)v[0]; hv[1] = (_Float16)v[1];
    hv[2] = (_Float16)v[2]; hv[3] = (_Float16)v[3];
    *(half4*)&x16[(t0g + tr) * 768 + c0 + cg] = hv;
    *(half4*)&lt[tr * 68 + cg] = hv;
  }
  __syncthreads();
  const int c = tid >> 2, tch = tid & 3;
  half8 o0, o1;
#pragma unroll
  for (int j = 0; j < 8; ++j) o0[j] = lt[(tch * 16 + j) * 68 + c];
#pragma unroll
  for (int j = 0; j < 8; ++j) o1[j] = lt[(tch * 16 + 8 + j) * 68 + c];
  _Float16* dst = xT + (long)b * 2408448 + (long)(c0 + c) * 3136 + tt * 64 + tch * 16;
  *(half8*)dst = o0;
  *(half8*)(dst + 8) = o1;
}

// ==================== Gram: G_b = xT_b . xT_b^T, symmetric 128^2 tiles ====================
__global__ __launch_bounds__(256)
void k_gram(const _Float16* __restrict__ xT, _Float16* __restrict__ G) {
  __shared__ _Float16 lds[2][2][128 * 32];
  const int tid = threadIdx.x;
  const int wv = tid >> 6, lane = tid & 63;
  const int g = lane >> 4, cidx = lane & 15;
  const int wr = wv >> 1, wc = wv & 1;

  const int nwg = (int)gridDim.x;
  const int q = nwg >> 3, r = nwg & 7;
  const int xcd = (int)blockIdx.x & 7, bidx = (int)blockIdx.x >> 3;
  int wg = (xcd < r ? xcd * (q + 1) : r * (q + 1) + (xcd - r) * q) + bidx;
  const int b = wg / 21;
  int p = wg % 21;
  int mt = 0;
  while (p >= 6 - mt) { p -= 6 - mt; ++mt; }
  const int nt = mt + p;

  const _Float16* Ab = xT + (long)b * 2408448 + (long)mt * 128 * 3136;
  const _Float16* Bb = xT + (long)b * 2408448 + (long)nt * 128 * 3136;

  const int srow = lane >> 2;
  const int sgr  = (lane & 3) ^ ((lane >> 3) & 3);

  auto stage = [&](int buf, int kt) {
#pragma unroll
    for (int l = 0; l < 2; ++l) {
      const int rbase = wv * 32 + l * 16;
      const long koff = (long)kt * 32 + sgr * 8;
      gload_lds16(Ab + (long)(rbase + srow) * 3136 + koff, &lds[buf][0][rbase * 32]);
      gload_lds16(Bb + (long)(rbase + srow) * 3136 + koff, &lds[buf][1][rbase * 32]);
    }
  };
  const int gr = (g ^ ((cidx >> 1) & 3)) * 8;

  f32x4 acc[4][4] = {};
  stage(0, 0);
  __syncthreads();
  for (int kt = 0; kt < 98; ++kt) {
    const int cur = kt & 1;
    if (kt + 1 < 98) stage(cur ^ 1, kt + 1);
    half8 af[4], bf[4];
#pragma unroll
    for (int m = 0; m < 4; ++m)
      af[m] = *(const half8*)&lds[cur][0][(wr * 64 + m * 16 + cidx) * 32 + gr];
#pragma unroll
    for (int n = 0; n < 4; ++n)
      bf[n] = *(const half8*)&lds[cur][1][(wc * 64 + n * 16 + cidx) * 32 + gr];
#pragma unroll
    for (int m = 0; m < 4; ++m)
#pragma unroll
      for (int n = 0; n < 4; ++n)
        acc[m][n] = MFMA_F16(af[m], bf[n], acc[m][n]);
    __syncthreads();
  }
  _Float16* Gb = G + (long)b * 589824;
  const long m0 = (long)mt * 128, n0 = (long)nt * 128;
#pragma unroll
  for (int m = 0; m < 4; ++m)
#pragma unroll
    for (int rr = 0; rr < 4; ++rr) {
      const long row = m0 + wr * 64 + m * 16 + g * 4 + rr;
#pragma unroll
      for (int n = 0; n < 4; ++n)
        Gb[row * 768 + n0 + wc * 64 + n * 16 + cidx] = (_Float16)acc[m][n][rr];
    }
  if (mt != nt) {
#pragma unroll
    for (int m = 0; m < 4; ++m)
#pragma unroll
      for (int n = 0; n < 4; ++n) {
        half4 hv;
#pragma unroll
        for (int rr = 0; rr < 4; ++rr) hv[rr] = (_Float16)acc[m][n][rr];
        const long col  = n0 + wc * 64 + n * 16 + cidx;
        const long row0 = m0 + wr * 64 + m * 16 + g * 4;
        *(half4*)&Gb[col * 768 + row0] = hv;
      }
  }
}

// ==================== generic batched 128^2 bt-GEMM (wfin) ====================
template<bool OUT_F32>
__global__ __launch_bounds__(256)
void k_g128(const _Float16* __restrict__ A, const _Float16* __restrict__ B,
            void* __restrict__ Cv, const float* __restrict__ bias,
            int Mt, int Nt, long Areal, long Astr, long Bstr, long Cstr,
            long N, long K)
{
  __shared__ _Float16 lds[2][2][128 * 32];
  const int tid = threadIdx.x;
  const int wv = tid >> 6, lane = tid & 63;
  const int g = lane >> 4, cidx = lane & 15;
  const int wr = wv >> 1, wc = wv & 1;

  const int nwg = (int)gridDim.x;
  const int q = nwg >> 3, r = nwg & 7;
  const int xcd = (int)blockIdx.x & 7, bidx = (int)blockIdx.x >> 3;
  int wg = (xcd < r ? xcd * (q + 1) : r * (q + 1) + (xcd - r) * q) + bidx;
  const int tpb = Mt * Nt;
  const int b = wg / tpb;
  const int rem = wg % tpb;
  const int mt = rem % Mt, nt = rem / Mt;
  const long m0 = (long)mt * 128, n0 = (long)nt * 128;

  const _Float16* Ab = A + b * Astr + m0 * K;
  const _Float16* Bb = B + b * Bstr + n0 * K;
  const int nkt = (int)(K >> 5);

  const int srow = lane >> 2;
  const int sgr  = (lane & 3) ^ ((lane >> 3) & 3);

  auto stage = [&](int buf, int kt) {
#pragma unroll
    for (int l = 0; l < 2; ++l) {
      const int rbase = wv * 32 + l * 16;
      const long koff = (long)kt * 32 + sgr * 8;
      gload_lds16(Ab + (long)(rbase + srow) * K + koff, &lds[buf][0][rbase * 32]);
      gload_lds16(Bb + (long)(rbase + srow) * K + koff, &lds[buf][1][rbase * 32]);
    }
  };
  const int gr = (g ^ ((cidx >> 1) & 3)) * 8;

  f32x4 acc[4][4] = {};
  stage(0, 0);
  __syncthreads();
  for (int kt = 0; kt < nkt; ++kt) {
    const int cur = kt & 1;
    if (kt + 1 < nkt) stage(cur ^ 1, kt + 1);
    half8 af[4], bf[4];
#pragma unroll
    for (int m = 0; m < 4; ++m)
      af[m] = *(const half8*)&lds[cur][0][(wr * 64 + m * 16 + cidx) * 32 + gr];
#pragma unroll
    for (int n = 0; n < 4; ++n)
      bf[n] = *(const half8*)&lds[cur][1][(wc * 64 + n * 16 + cidx) * 32 + gr];
#pragma unroll
    for (int m = 0; m < 4; ++m)
#pragma unroll
      for (int n = 0; n < 4; ++n)
        acc[m][n] = MFMA_F16(af[m], bf[n], acc[m][n]);
    __syncthreads();
  }

  float bv[4] = {0.f, 0.f, 0.f, 0.f};
  if (bias) {
#pragma unroll
    for (int n = 0; n < 4; ++n) bv[n] = bias[n0 + wc * 64 + n * 16 + cidx];
  }
  if constexpr (OUT_F32) {
    float* C = (float*)Cv + b * Cstr;
#pragma unroll
    for (int m = 0; m < 4; ++m)
#pragma unroll
      for (int rr = 0; rr < 4; ++rr) {
        const long row = m0 + wr * 64 + m * 16 + g * 4 + rr;
        if (row < Areal) {
#pragma unroll
          for (int n = 0; n < 4; ++n)
            C[row * N + n0 + wc * 64 + n * 16 + cidx] = acc[m][n][rr] + bv[n];
        }
      }
  } else {
    _Float16* C = (_Float16*)Cv + b * Cstr;
#pragma unroll
    for (int m = 0; m < 4; ++m)
#pragma unroll
      for (int rr = 0; rr < 4; ++rr) {
        const long row = m0 + wr * 64 + m * 16 + g * 4 + rr;
        if (row < Areal) {
#pragma unroll
          for (int n = 0; n < 4; ++n)
            C[row * N + n0 + wc * 64 + n * 16 + cidx] = (_Float16)acc[m][n][rr];
        }
      }
  }
}

// ==================== 256x256 8-phase bt-GEMM, batched + M-tail mask ====================
template<bool OUT_F32>
__global__ __launch_bounds__(512, 2)
void k_gemm8p(const _Float16* __restrict__ A, const _Float16* __restrict__ B,
              void* __restrict__ Cv, const float* __restrict__ bias,
              int Mt, int Nt, long Areal, long Astr, long Bstr, long Cstr,
              long N, long K)
{
  __shared__ _Float16 lds[65536];  // 128 KiB
  const int tid  = threadIdx.x;
  const int wv   = tid >> 6, lane = tid & 63;
  const int g    = lane >> 4, cidx = lane & 15;
  const int wr   = wv >> 2, wc = wv & 3;

  const int nwg = (int)gridDim.x;
  const int q = nwg >> 3, r = nwg & 7;
  const int xcd = (int)blockIdx.x & 7, bidx = (int)blockIdx.x >> 3;
  int wg = (xcd < r ? xcd * (q + 1) : r * (q + 1) + (xcd - r) * q) + bidx;

  const int tpb = Mt * Nt;
  const int b   = wg / tpb;
  const int rem = wg - b * tpb;
  const long mt = rem % Mt, nt = rem / Mt;
  const long m0 = mt * 256, n0 = nt * 256;

  const int NT = (int)(K >> 6);
  const int NI = NT >> 1;

  const _Float16* Ab = A + b * Astr + m0 * K;
  const _Float16* Bb = B + b * Bstr + n0 * K;

  const int srow = lane >> 2;
  const int sgr  = (lane & 3) ^ ((lane >> 3) & 3);

  auto stage = [&](int op, int buf, int kh, int t) {
    const _Float16* src = op ? Bb : Ab;
    const long koff = (long)t * 64 + kh * 32 + sgr * 8;
#pragma unroll
    for (int l = 0; l < 2; ++l) {
      const int chunk = l * 8 + wv;
      gload_lds16(src + (long)(chunk * 16 + srow) * K + koff,
                  &lds[buf * 32768 + op * 16384 + kh * 8192 + chunk * 512]);
    }
  };

  const int gr  = (g ^ ((cidx >> 1) & 3)) * 8;
  const int raA = (wr * 128 + cidx) * 32 + gr;
  const int raB = 16384 + (wc * 64 + cidx) * 32 + gr;

  f32x4 acc[8][4] = {};

  stage(0, 0, 0, 0); stage(1, 0, 0, 0);
  stage(0, 0, 1, 0); stage(1, 0, 1, 0);
  stage(0, 1, 0, 1); stage(1, 1, 0, 1);
  asm volatile("s_waitcnt vmcnt(4)" ::: "memory");
  __builtin_amdgcn_sched_barrier(0);
  __builtin_amdgcn_s_barrier();

  half8 afA[4], afB[4], bfA[4], bfB[4];
#pragma unroll
  for (int mm = 0; mm < 4; ++mm) afA[mm] = *(const half8*)&lds[raA + mm * 512];
#pragma unroll
  for (int nn = 0; nn < 4; ++nn) bfA[nn] = *(const half8*)&lds[raB + nn * 512];

#define XPH(CURA, CURB, MLO, NA, NBUF, NKS, NMLO, LOADB, NB, STAGE, BDRY)      \
  {                                                                            \
    STAGE;                                                                     \
    if (BDRY) {                                                                \
      asm volatile("s_waitcnt vmcnt(4)" ::: "memory");                         \
      __builtin_amdgcn_sched_barrier(0);                                       \
    }                                                                          \
    __builtin_amdgcn_s_barrier();                                              \
    _Pragma("unroll")                                                          \
    for (int mm = 0; mm < 4; ++mm)                                             \
      NA[mm] = *(const half8*)&lds[(NBUF)*32768 + (NKS)*8192 + raA + ((NMLO)+mm)*512]; \
    if (LOADB) {                                                               \
      _Pragma("unroll")                                                        \
      for (int nn = 0; nn < 4; ++nn)                                           \
        NB[nn] = *(const half8*)&lds[(NBUF)*32768 + (NKS)*8192 + raB + nn*512]; \
    }                                                                          \
    __builtin_amdgcn_sched_barrier(0);                                         \
    __builtin_amdgcn_s_setprio(1);                                             \
    _Pragma("unroll")                                                          \
    for (int mm = 0; mm < 4; ++mm)                                             \
      _Pragma("unroll")                                                        \
      for (int nn = 0; nn < 4; ++nn)                                           \
        acc[(MLO)+mm][nn] = MFMA_F16(CURA[mm], CURB[nn], acc[(MLO)+mm][nn]);   \
    __builtin_amdgcn_s_setprio(0);                                             \
    __builtin_amdgcn_s_barrier();                                              \
  }

  for (int it = 0; it < NI; ++it) {
    const int t1c = 2 * it + 1;
    int tn2 = 2 * it + 2; if (tn2 >= NT) tn2 -= NT;
    int tn3 = 2 * it + 3; if (tn3 >= NT) tn3 -= NT;
    XPH(afA, bfA, 0, afB, 0, 0, 4, 0, bfB, stage(0, 1, 1, t1c), false)
    XPH(afB, bfA, 4, afA, 0, 1, 0, 1, bfB, stage(1, 1, 1, t1c), false)
    XPH(afA, bfB, 0, afB, 0, 1, 4, 0, bfA, stage(0, 0, 0, tn2), false)
    XPH(afB, bfB, 4, afA, 1, 0, 0, 1, bfA, stage(1, 0, 0, tn2), true )
    XPH(afA, bfA, 0, afB, 1, 0, 4, 0, bfB, stage(0, 0, 1, tn2), false)
    XPH(afB, bfA, 4, afA, 1, 1, 0, 1, bfB, stage(1, 0, 1, tn2), false)
    XPH(afA, bfB, 0, afB, 1, 1, 4, 0, bfA, stage(0, 1, 0, tn3), false)
    XPH(afB, bfB, 4, afA, 0, 0, 0, 1, bfA, stage(1, 1, 0, tn3), true )
  }
#undef XPH

  float bv[4] = {0.f, 0.f, 0.f, 0.f};
  if (bias) {
#pragma unroll
    for (int n = 0; n < 4; ++n) bv[n] = bias[n0 + wc * 64 + n * 16 + cidx];
  }
  if constexpr (OUT_F32) {
    float* C = (float*)Cv + b * Cstr;
#pragma unroll
    for (int m = 0; m < 8; ++m)
#pragma unroll
      for (int rr = 0; rr < 4; ++rr) {
        const long row = m0 + wr * 128 + m * 16 + g * 4 + rr;
        if (row < Areal) {
#pragma unroll
          for (int n = 0; n < 4; ++n)
            C[row * N + (n0 + wc * 64 + n * 16 + cidx)] = acc[m][n][rr] + bv[n];
        }
      }
  } else {
    _Float16* C = (_Float16*)Cv + b * Cstr;
#pragma unroll
    for (int m = 0; m < 8; ++m)
#pragma unroll
      for (int rr = 0; rr < 4; ++rr) {
        const long row = m0 + wr * 128 + m * 16 + g * 4 + rr;
        if (row < Areal) {
#pragma unroll
          for (int n = 0; n < 4; ++n)
            C[row * N + (n0 + wc * 64 + n * 16 + cidx)] = (_Float16)acc[m][n][rr];
        }
      }
  }
}

// ==================== heads: S/norms from QG, softmax, WeffT. One block per (b,h) ====================
// S = T1.Wk^T, qn = diag(T1.Wq^T), kn = diag(T3.Wk^T), T1/T3 = QG_b q/k bands.
__global__ __launch_bounds__(256)
void k_heads(const _Float16* __restrict__ QG, const _Float16* __restrict__ w16,
             const _Float16* __restrict__ wvT, const float* __restrict__ temperature,
             _Float16* __restrict__ weffT)
{
  const int b = blockIdx.x >> 4, h = blockIdx.x & 15;
  const int tid = threadIdx.x;
  const int w = tid >> 6, lane = tid & 63;
  const int g = lane >> 4, c = lane & 15;

  __shared__ float red[4][48 * 48];
  __shared__ float redss[4][2][48];
  __shared__ float inv[2][48];
  __shared__ _Float16 Pb[48 * 64];

  const _Float16* QGq = QG + (long)b * 1179648 + (long)(h * 48) * 768;
  const _Float16* QGk = QGq + 768L * 768;
  const _Float16* Wq  = w16 + (long)(h * 48) * 768;
  const _Float16* Wk  = w16 + (long)(768 + h * 48) * 768;

  f32x4 aS[3][3] = {};
  f32x4 aq[3] = {};
  f32x4 ak[3] = {};
  for (int ks = w * 6; ks < w * 6 + 6; ++ks) {
    const int k0 = ks * 32 + g * 8;
    half8 t1[3], t3[3], wqf[3], wkf[3];
#pragma unroll
    for (int m = 0; m < 3; ++m) {
      const long ro = (long)(m * 16 + c) * 768 + k0;
      t1[m]  = *(const half8*)(QGq + ro);
      t3[m]  = *(const half8*)(QGk + ro);
      wqf[m] = *(const half8*)(Wq + ro);
      wkf[m] = *(const half8*)(Wk + ro);
    }
#pragma unroll
    for (int m = 0; m < 3; ++m) {
      aq[m] = MFMA_F16(t1[m], wqf[m], aq[m]);
      ak[m] = MFMA_F16(t3[m], wkf[m], ak[m]);
#pragma unroll
      for (int n = 0; n < 3; ++n)
        aS[m][n] = MFMA_F16(t1[m], wkf[n], aS[m][n]);
    }
  }

#pragma unroll
  for (int m = 0; m < 3; ++m) {
#pragma unroll
    for (int n = 0; n < 3; ++n)
#pragma unroll
      for (int rr = 0; rr < 4; ++rr)
        red[w][(m * 16 + g * 4 + rr) * 48 + n * 16 + c] = aS[m][n][rr];
#pragma unroll
    for (int rr = 0; rr < 4; ++rr)
      if (c == g * 4 + rr) {
        redss[w][0][m * 16 + c] = aq[m][rr];
        redss[w][1][m * 16 + c] = ak[m][rr];
      }
  }
  __syncthreads();

  if (tid < 96) {
    const int is_k = tid / 48, d = tid % 48;
    const float s = redss[0][is_k][d] + redss[1][is_k][d] + redss[2][is_k][d] + redss[3][is_k][d];
    inv[is_k][d] = 1.0f / fmaxf(sqrtf(s), 1e-12f);
  }
  __syncthreads();

  if (tid < 48) {
    const int d = tid;
    const float iq = inv[0][d] * temperature[h];
    float rowv[48];
    float mx = -3.0e38f;
#pragma unroll
    for (int e = 0; e < 48; ++e) {
      const int idx = d * 48 + e;
      float t = (red[0][idx] + red[1][idx] + red[2][idx] + red[3][idx]) * iq * inv[1][e];
      rowv[e] = t;
      mx = fmaxf(mx, t);
    }
    float sum = 0.f;
#pragma unroll
    for (int e = 0; e < 48; ++e) {
      const float pv = __expf(rowv[e] - mx);
      rowv[e] = pv;
      sum += pv;
    }
    const float is = 1.0f / sum;
#pragma unroll
    for (int e = 0; e < 48; ++e)
      Pb[d * 64 + e] = (_Float16)(rowv[e] * is);
#pragma unroll
    for (int e = 48; e < 64; ++e)
      Pb[d * 64 + e] = (_Float16)0.f;
  }
  __syncthreads();

  // WeffT_b[f][h*48+d] = sum_e wvT[h][f][e] P[d][e]
  half8 pf[3][2];
#pragma unroll
  for (int nf = 0; nf < 3; ++nf)
#pragma unroll
    for (int ks = 0; ks < 2; ++ks)
      pf[nf][ks] = *(const half8*)&Pb[(nf * 16 + c) * 64 + ks * 32 + g * 8];

  const _Float16* wvh = wvT + (long)h * 768 * 64;
  _Float16* wout = weffT + (long)b * 589824 + h * 48;

  for (int m = 0; m < 12; ++m) {
    const int f0 = w * 192 + m * 16;
    half8 va[2];
#pragma unroll
    for (int ks = 0; ks < 2; ++ks)
      va[ks] = *(const half8*)&wvh[(long)(f0 + c) * 64 + ks * 32 + g * 8];
    f32x4 a3[3] = {};
#pragma unroll
    for (int ks = 0; ks < 2; ++ks)
#pragma unroll
      for (int nf = 0; nf < 3; ++nf)
        a3[nf] = MFMA_F16(va[ks], pf[nf][ks], a3[nf]);
#pragma unroll
    for (int nf = 0; nf < 3; ++nf)
#pragma unroll
      for (int rr = 0; rr < 4; ++rr)
        wout[(long)(f0 + g * 4 + rr) * 768 + nf * 16 + c] = (_Float16)a3[nf][rr];
  }
}

// -------------------- launch --------------------
extern "C" void kernel_launch(void* const* d_in, const int* in_sizes, int n_in,
                              void* d_out, int out_size, void* d_ws, size_t ws_size,
                              hipStream_t stream)
{
  (void)in_sizes; (void)n_in; (void)out_size; (void)ws_size;
  const float* x      = (const float*)d_in[0];
  const float* w_qkv  = (const float*)d_in[1];
  const float* temp   = (const float*)d_in[2];
  const float* w_proj = (const float*)d_in[3];
  const float* b_proj = (const float*)d_in[4];
  float* out = (float*)d_out;

  // ws layout (bytes):
  //   [0)          x16   : 77,070,336   [50176][768]
  //   [77070336)   xT    : 77,070,336   [16][768][3136]
  //   [154140672)  G     : 18,874,368   [16][768][768]
  //   [173015040)  QG    : 37,748,736   [16][1536][768]
  //   [210763776)  weffT : 18,874,368   [16][768 f][768 c]
  //   [229638144)  wfin  : 18,874,368   [16][768 o][768 f]
  //   [248512512)  w16   : 3,538,944
  //   [252051456)  wp16  : 1,179,648
  //   [253231104)  wvT   : 1,572,864
  char* ws = (char*)d_ws;
  _Float16* x16   = (_Float16*)(ws);
  _Float16* xT    = (_Float16*)(ws + 77070336L);
  _Float16* G     = (_Float16*)(ws + 154140672L);
  _Float16* QG    = (_Float16*)(ws + 173015040L);
  _Float16* weffT = (_Float16*)(ws + 210763776L);
  _Float16* wfin  = (_Float16*)(ws + 229638144L);
  _Float16* w16   = (_Float16*)(ws + 248512512L);
  _Float16* wp16  = (_Float16*)(ws + 252051456L);
  _Float16* wvT   = (_Float16*)(ws + 253231104L);

  k_cvtw<<<768, 256, 0, stream>>>(w_qkv, w_proj, w16, wp16, wvT);
  k_cvtx<<<9408, 256, 0, stream>>>(x, x16, xT);
  // G_b = xT_b . xT_b^T (symmetric)
  k_gram<<<336, 256, 0, stream>>>(xT, G);
  // QG_b = w16[0:1536] . G_b  (8-phase 256^2: 6 Mt x 3 Nt x 16 batches = 288 blocks)
  k_gemm8p<false><<<288, 512, 0, stream>>>(w16, G, QG, nullptr,
                                           6, 3, 1536, 0, 589824, 1179648, 768, 768);
  // per (b,h): S, norms, softmax, WeffT
  k_heads<<<256, 256, 0, stream>>>(QG, w16, wvT, temp, weffT);
  // wfin_b = Wp . Weff_b
  k_g128<false><<<576, 256, 0, stream>>>(wp16, weffT, wfin, nullptr,
                                         6, 6, 768, 0, 589824, 589824, 768, 768);
  // out_b[t][o] = x16_b[t,:] . wfin_b[o,:] + bias  (fp32, 8-phase, M-tail masked)
  k_gemm8p<true><<<624, 512, 0, stream>>>(x16, wfin, out, b_proj,
                                          13, 3, 3136, 3136L * 768, 589824, 3136L * 768,
                                          768, 768);
}

// Round 10
// 319.664 us; speedup vs baseline: 1.2799x; 1.0603x over previous
//
#include <hip/hip_runtime.h>
#include <hip/hip_bf16.h>
#include <stdint.h>

using f32x4   = __attribute__((ext_vector_type(4))) float;
using half8   = __attribute__((ext_vector_type(8))) _Float16;
using half4   = __attribute__((ext_vector_type(4))) _Float16;
using float4v = __attribute__((ext_vector_type(4))) float;

typedef const __attribute__((address_space(1))) void gas_void;
typedef __attribute__((address_space(3))) void las_void;

__device__ __forceinline__ void gload_lds16(const void* gptr, void* lptr) {
  __builtin_amdgcn_global_load_lds((gas_void*)(uintptr_t)gptr,
                                   (las_void*)(uintptr_t)lptr, 16, 0, 0);
}

#define MFMA_F16(a, b, c) __builtin_amdgcn_mfma_f32_16x16x32_f16((a), (b), (c), 0, 0, 0)

// ---------- x fp32 -> x16 [50176][768] AND xT [16][768][3136]; tail blocks do weights ----------
__global__ __launch_bounds__(256)
void k_cvtx(const float* __restrict__ x, _Float16* __restrict__ x16,
            _Float16* __restrict__ xT,
            const float* __restrict__ wqkv, const float* __restrict__ wproj,
            _Float16* __restrict__ w16, _Float16* __restrict__ wp16,
            _Float16* __restrict__ wvT) {
  const int bid = blockIdx.x;
  if (bid >= 9408) {
    // ---- weight convert (grid-stride over 512 tail blocks) ----
    const long N1 = 221184L, N2 = 73728L, N3 = 98304L;  // 8-elem units
    const long total = N1 + N2 + N3;
    for (long i = (long)(bid - 9408) * blockDim.x + threadIdx.x; i < total;
         i += 512L * blockDim.x) {
      if (i < N1 + N2) {
        const float* src; _Float16* dst; long off;
        if (i < N1) { src = wqkv;  dst = w16;  off = i; }
        else        { src = wproj; dst = wp16; off = i - N1; }
        const float4v* p = (const float4v*)(src + off * 8);
        float4v a = p[0], b = p[1];
        half8 o;
        o[0] = (_Float16)a[0]; o[1] = (_Float16)a[1]; o[2] = (_Float16)a[2]; o[3] = (_Float16)a[3];
        o[4] = (_Float16)b[0]; o[5] = (_Float16)b[1]; o[6] = (_Float16)b[2]; o[7] = (_Float16)b[3];
        *(half8*)(dst + off * 8) = o;
      } else {
        const long u = i - N1 - N2;
        const int h = (int)(u / 6144);
        const int r = (int)(u % 6144);
        const int f = r >> 3, e0 = (r & 7) * 8;
        half8 o;
        if (e0 >= 48) {
#pragma unroll
          for (int j = 0; j < 8; ++j) o[j] = (_Float16)0.f;
        } else {
#pragma unroll
          for (int j = 0; j < 8; ++j)
            o[j] = (_Float16)wqkv[(long)(1536 + h * 48 + e0 + j) * 768 + f];
        }
        *(half8*)(wvT + ((long)(h * 768 + f) * 64 + e0)) = o;
      }
    }
    return;
  }
  __shared__ _Float16 lt[64 * 68];
  const int b = bid / 588;
  const int rem = bid % 588;
  const int tt = rem / 12, ct = rem % 12;
  const long t0g = (long)b * 3136 + tt * 64;
  const int c0 = ct * 64;
  const int tid = threadIdx.x;
#pragma unroll
  for (int ch = 0; ch < 4; ++ch) {
    const int idx = tid + ch * 256;
    const int tr = idx >> 4, cg = (idx & 15) * 4;
    float4v v = *(const float4v*)&x[(t0g + tr) * 768 + c0 + cg];
    half4 hv;
    hv[0] = (_Float16)v[0]; hv[1] = (_Float16)v[1];
    hv[2] = (_Float16)v[2]; hv[3] = (_Float16)v[3];
    *(half4*)&x16[(t0g + tr) * 768 + c0 + cg] = hv;
    *(half4*)&lt[tr * 68 + cg] = hv;
  }
  __syncthreads();
  const int c = tid >> 2, tch = tid & 3;
  half8 o0, o1;
#pragma unroll
  for (int j = 0; j < 8; ++j) o0[j] = lt[(tch * 16 + j) * 68 + c];
#pragma unroll
  for (int j = 0; j < 8; ++j) o1[j] = lt[(tch * 16 + 8 + j) * 68 + c];
  _Float16* dst = xT + (long)b * 2408448 + (long)(c0 + c) * 3136 + tt * 64 + tch * 16;
  *(half8*)dst = o0;
  *(half8*)(dst + 8) = o1;
}

// ==================== Gram: G_b = xT_b . xT_b^T, symmetric 128^2 tiles ====================
// 512 thr = 8 waves (2M x 4N), wave tile 64x32, BK=64 (49 K-tiles), 64 KiB LDS dbuf.
// Swizzle for 128-B rows: granule' = granule ^ (row&7); linear LDS dest via
// pre-swizzled source granule (lane&7)^(lane>>3).
__global__ __launch_bounds__(512)
void k_gram(const _Float16* __restrict__ xT, _Float16* __restrict__ G) {
  __shared__ _Float16 lds[2][2][128 * 64];   // 64 KiB
  const int tid = threadIdx.x;
  const int wv = tid >> 6, lane = tid & 63;
  const int g = lane >> 4, cidx = lane & 15;
  const int wr = wv >> 2, wc = wv & 3;

  const int nwg = (int)gridDim.x;
  const int q = nwg >> 3, r = nwg & 7;
  const int xcd = (int)blockIdx.x & 7, bidx = (int)blockIdx.x >> 3;
  int wg = (xcd < r ? xcd * (q + 1) : r * (q + 1) + (xcd - r) * q) + bidx;
  const int b = wg / 21;
  int p = wg % 21;
  int mt = 0;
  while (p >= 6 - mt) { p -= 6 - mt; ++mt; }
  const int nt = mt + p;

  const _Float16* Ab = xT + (long)b * 2408448 + (long)mt * 128 * 3136;
  const _Float16* Bb = xT + (long)b * 2408448 + (long)nt * 128 * 3136;

  // staging: chunk = 8 rows x 128 B; 16 chunks per op; wave wv covers l*8+wv.
  const int srow8 = lane >> 3;               // row within chunk
  const int sgr8  = (lane & 7) ^ srow8;      // pre-swizzled source granule

  auto stage = [&](int buf, int kt) {
#pragma unroll
    for (int l = 0; l < 2; ++l) {
      const int chunk = l * 8 + wv;
      const long grow = chunk * 8 + srow8;
      const long koff = (long)kt * 64 + sgr8 * 8;
      gload_lds16(Ab + grow * 3136 + koff, &lds[buf][0][chunk * 512]);
      gload_lds16(Bb + grow * 3136 + koff, &lds[buf][1][chunk * 512]);
    }
  };

  f32x4 acc[4][2] = {};
  stage(0, 0);
  __syncthreads();
  for (int kt = 0; kt < 49; ++kt) {
    const int cur = kt & 1;
    if (kt + 1 < 49) stage(cur ^ 1, kt + 1);
    half8 af[4][2], bf[2][2];
#pragma unroll
    for (int ks = 0; ks < 2; ++ks) {
      const int gran = (((ks << 2) + g) ^ (cidx & 7)) * 8;
#pragma unroll
      for (int m = 0; m < 4; ++m)
        af[m][ks] = *(const half8*)&lds[cur][0][(wr * 64 + m * 16 + cidx) * 64 + gran];
#pragma unroll
      for (int n = 0; n < 2; ++n)
        bf[n][ks] = *(const half8*)&lds[cur][1][(wc * 32 + n * 16 + cidx) * 64 + gran];
    }
#pragma unroll
    for (int ks = 0; ks < 2; ++ks)
#pragma unroll
      for (int m = 0; m < 4; ++m)
#pragma unroll
        for (int n = 0; n < 2; ++n)
          acc[m][n] = MFMA_F16(af[m][ks], bf[n][ks], acc[m][n]);
    __syncthreads();
  }
  _Float16* Gb = G + (long)b * 589824;
  const long m0 = (long)mt * 128, n0 = (long)nt * 128;
#pragma unroll
  for (int m = 0; m < 4; ++m)
#pragma unroll
    for (int rr = 0; rr < 4; ++rr) {
      const long row = m0 + wr * 64 + m * 16 + g * 4 + rr;
#pragma unroll
      for (int n = 0; n < 2; ++n)
        Gb[row * 768 + n0 + wc * 32 + n * 16 + cidx] = (_Float16)acc[m][n][rr];
    }
  if (mt != nt) {
#pragma unroll
    for (int m = 0; m < 4; ++m)
#pragma unroll
      for (int n = 0; n < 2; ++n) {
        half4 hv;
#pragma unroll
        for (int rr = 0; rr < 4; ++rr) hv[rr] = (_Float16)acc[m][n][rr];
        const long col  = n0 + wc * 32 + n * 16 + cidx;
        const long row0 = m0 + wr * 64 + m * 16 + g * 4;
        *(half4*)&Gb[col * 768 + row0] = hv;
      }
  }
}

// ==================== generic batched 128^2 bt-GEMM (wfin) ====================
template<bool OUT_F32>
__global__ __launch_bounds__(256)
void k_g128(const _Float16* __restrict__ A, const _Float16* __restrict__ B,
            void* __restrict__ Cv, const float* __restrict__ bias,
            int Mt, int Nt, long Areal, long Astr, long Bstr, long Cstr,
            long N, long K)
{
  __shared__ _Float16 lds[2][2][128 * 32];
  const int tid = threadIdx.x;
  const int wv = tid >> 6, lane = tid & 63;
  const int g = lane >> 4, cidx = lane & 15;
  const int wr = wv >> 1, wc = wv & 1;

  const int nwg = (int)gridDim.x;
  const int q = nwg >> 3, r = nwg & 7;
  const int xcd = (int)blockIdx.x & 7, bidx = (int)blockIdx.x >> 3;
  int wg = (xcd < r ? xcd * (q + 1) : r * (q + 1) + (xcd - r) * q) + bidx;
  const int tpb = Mt * Nt;
  const int b = wg / tpb;
  const int rem = wg % tpb;
  const int mt = rem % Mt, nt = rem / Mt;
  const long m0 = (long)mt * 128, n0 = (long)nt * 128;

  const _Float16* Ab = A + b * Astr + m0 * K;
  const _Float16* Bb = B + b * Bstr + n0 * K;
  const int nkt = (int)(K >> 5);

  const int srow = lane >> 2;
  const int sgr  = (lane & 3) ^ ((lane >> 3) & 3);

  auto stage = [&](int buf, int kt) {
#pragma unroll
    for (int l = 0; l < 2; ++l) {
      const int rbase = wv * 32 + l * 16;
      const long koff = (long)kt * 32 + sgr * 8;
      gload_lds16(Ab + (long)(rbase + srow) * K + koff, &lds[buf][0][rbase * 32]);
      gload_lds16(Bb + (long)(rbase + srow) * K + koff, &lds[buf][1][rbase * 32]);
    }
  };
  const int gr = (g ^ ((cidx >> 1) & 3)) * 8;

  f32x4 acc[4][4] = {};
  stage(0, 0);
  __syncthreads();
  for (int kt = 0; kt < nkt; ++kt) {
    const int cur = kt & 1;
    if (kt + 1 < nkt) stage(cur ^ 1, kt + 1);
    half8 af[4], bf[4];
#pragma unroll
    for (int m = 0; m < 4; ++m)
      af[m] = *(const half8*)&lds[cur][0][(wr * 64 + m * 16 + cidx) * 32 + gr];
#pragma unroll
    for (int n = 0; n < 4; ++n)
      bf[n] = *(const half8*)&lds[cur][1][(wc * 64 + n * 16 + cidx) * 32 + gr];
#pragma unroll
    for (int m = 0; m < 4; ++m)
#pragma unroll
      for (int n = 0; n < 4; ++n)
        acc[m][n] = MFMA_F16(af[m], bf[n], acc[m][n]);
    __syncthreads();
  }

  float bv[4] = {0.f, 0.f, 0.f, 0.f};
  if (bias) {
#pragma unroll
    for (int n = 0; n < 4; ++n) bv[n] = bias[n0 + wc * 64 + n * 16 + cidx];
  }
  if constexpr (OUT_F32) {
    float* C = (float*)Cv + b * Cstr;
#pragma unroll
    for (int m = 0; m < 4; ++m)
#pragma unroll
      for (int rr = 0; rr < 4; ++rr) {
        const long row = m0 + wr * 64 + m * 16 + g * 4 + rr;
        if (row < Areal) {
#pragma unroll
          for (int n = 0; n < 4; ++n)
            C[row * N + n0 + wc * 64 + n * 16 + cidx] = acc[m][n][rr] + bv[n];
        }
      }
  } else {
    _Float16* C = (_Float16*)Cv + b * Cstr;
#pragma unroll
    for (int m = 0; m < 4; ++m)
#pragma unroll
      for (int rr = 0; rr < 4; ++rr) {
        const long row = m0 + wr * 64 + m * 16 + g * 4 + rr;
        if (row < Areal) {
#pragma unroll
          for (int n = 0; n < 4; ++n)
            C[row * N + n0 + wc * 64 + n * 16 + cidx] = (_Float16)acc[m][n][rr];
        }
      }
  }
}

// ==================== 256x256 8-phase bt-GEMM, batched + M-tail mask ====================
template<bool OUT_F32>
__global__ __launch_bounds__(512, 2)
void k_gemm8p(const _Float16* __restrict__ A, const _Float16* __restrict__ B,
              void* __restrict__ Cv, const float* __restrict__ bias,
              int Mt, int Nt, long Areal, long Astr, long Bstr, long Cstr,
              long N, long K)
{
  __shared__ _Float16 lds[65536];  // 128 KiB
  const int tid  = threadIdx.x;
  const int wv   = tid >> 6, lane = tid & 63;
  const int g    = lane >> 4, cidx = lane & 15;
  const int wr   = wv >> 2, wc = wv & 3;

  const int nwg = (int)gridDim.x;
  const int q = nwg >> 3, r = nwg & 7;
  const int xcd = (int)blockIdx.x & 7, bidx = (int)blockIdx.x >> 3;
  int wg = (xcd < r ? xcd * (q + 1) : r * (q + 1) + (xcd - r) * q) + bidx;

  const int tpb = Mt * Nt;
  const int b   = wg / tpb;
  const int rem = wg - b * tpb;
  const long mt = rem % Mt, nt = rem / Mt;
  const long m0 = mt * 256, n0 = nt * 256;

  const int NT = (int)(K >> 6);
  const int NI = NT >> 1;

  const _Float16* Ab = A + b * Astr + m0 * K;
  const _Float16* Bb = B + b * Bstr + n0 * K;

  const int srow = lane >> 2;
  const int sgr  = (lane & 3) ^ ((lane >> 3) & 3);

  auto stage = [&](int op, int buf, int kh, int t) {
    const _Float16* src = op ? Bb : Ab;
    const long koff = (long)t * 64 + kh * 32 + sgr * 8;
#pragma unroll
    for (int l = 0; l < 2; ++l) {
      const int chunk = l * 8 + wv;
      gload_lds16(src + (long)(chunk * 16 + srow) * K + koff,
                  &lds[buf * 32768 + op * 16384 + kh * 8192 + chunk * 512]);
    }
  };

  const int gr  = (g ^ ((cidx >> 1) & 3)) * 8;
  const int raA = (wr * 128 + cidx) * 32 + gr;
  const int raB = 16384 + (wc * 64 + cidx) * 32 + gr;

  f32x4 acc[8][4] = {};

  stage(0, 0, 0, 0); stage(1, 0, 0, 0);
  stage(0, 0, 1, 0); stage(1, 0, 1, 0);
  stage(0, 1, 0, 1); stage(1, 1, 0, 1);
  asm volatile("s_waitcnt vmcnt(4)" ::: "memory");
  __builtin_amdgcn_sched_barrier(0);
  __builtin_amdgcn_s_barrier();

  half8 afA[4], afB[4], bfA[4], bfB[4];
#pragma unroll
  for (int mm = 0; mm < 4; ++mm) afA[mm] = *(const half8*)&lds[raA + mm * 512];
#pragma unroll
  for (int nn = 0; nn < 4; ++nn) bfA[nn] = *(const half8*)&lds[raB + nn * 512];

#define XPH(CURA, CURB, MLO, NA, NBUF, NKS, NMLO, LOADB, NB, STAGE, BDRY)      \
  {                                                                            \
    STAGE;                                                                     \
    if (BDRY) {                                                                \
      asm volatile("s_waitcnt vmcnt(4)" ::: "memory");                         \
      __builtin_amdgcn_sched_barrier(0);                                       \
    }                                                                          \
    __builtin_amdgcn_s_barrier();                                              \
    _Pragma("unroll")                                                          \
    for (int mm = 0; mm < 4; ++mm)                                             \
      NA[mm] = *(const half8*)&lds[(NBUF)*32768 + (NKS)*8192 + raA + ((NMLO)+mm)*512]; \
    if (LOADB) {                                                               \
      _Pragma("unroll")                                                        \
      for (int nn = 0; nn < 4; ++nn)                                           \
        NB[nn] = *(const half8*)&lds[(NBUF)*32768 + (NKS)*8192 + raB + nn*512]; \
    }                                                                          \
    __builtin_amdgcn_sched_barrier(0);                                         \
    __builtin_amdgcn_s_setprio(1);                                             \
    _Pragma("unroll")                                                          \
    for (int mm = 0; mm < 4; ++mm)                                             \
      _Pragma("unroll")                                                        \
      for (int nn = 0; nn < 4; ++nn)                                           \
        acc[(MLO)+mm][nn] = MFMA_F16(CURA[mm], CURB[nn], acc[(MLO)+mm][nn]);   \
    __builtin_amdgcn_s_setprio(0);                                             \
    __builtin_amdgcn_s_barrier();                                              \
  }

  for (int it = 0; it < NI; ++it) {
    const int t1c = 2 * it + 1;
    int tn2 = 2 * it + 2; if (tn2 >= NT) tn2 -= NT;
    int tn3 = 2 * it + 3; if (tn3 >= NT) tn3 -= NT;
    XPH(afA, bfA, 0, afB, 0, 0, 4, 0, bfB, stage(0, 1, 1, t1c), false)
    XPH(afB, bfA, 4, afA, 0, 1, 0, 1, bfB, stage(1, 1, 1, t1c), false)
    XPH(afA, bfB, 0, afB, 0, 1, 4, 0, bfA, stage(0, 0, 0, tn2), false)
    XPH(afB, bfB, 4, afA, 1, 0, 0, 1, bfA, stage(1, 0, 0, tn2), true )
    XPH(afA, bfA, 0, afB, 1, 0, 4, 0, bfB, stage(0, 0, 1, tn2), false)
    XPH(afB, bfA, 4, afA, 1, 1, 0, 1, bfB, stage(1, 0, 1, tn2), false)
    XPH(afA, bfB, 0, afB, 1, 1, 4, 0, bfA, stage(0, 1, 0, tn3), false)
    XPH(afB, bfB, 4, afA, 0, 0, 0, 1, bfA, stage(1, 1, 0, tn3), true )
  }
#undef XPH

  float bv[4] = {0.f, 0.f, 0.f, 0.f};
  if (bias) {
#pragma unroll
    for (int n = 0; n < 4; ++n) bv[n] = bias[n0 + wc * 64 + n * 16 + cidx];
  }
  if constexpr (OUT_F32) {
    float* C = (float*)Cv + b * Cstr;
#pragma unroll
    for (int m = 0; m < 8; ++m)
#pragma unroll
      for (int rr = 0; rr < 4; ++rr) {
        const long row = m0 + wr * 128 + m * 16 + g * 4 + rr;
        if (row < Areal) {
#pragma unroll
          for (int n = 0; n < 4; ++n)
            C[row * N + (n0 + wc * 64 + n * 16 + cidx)] = acc[m][n][rr] + bv[n];
        }
      }
  } else {
    _Float16* C = (_Float16*)Cv + b * Cstr;
#pragma unroll
    for (int m = 0; m < 8; ++m)
#pragma unroll
      for (int rr = 0; rr < 4; ++rr) {
        const long row = m0 + wr * 128 + m * 16 + g * 4 + rr;
        if (row < Areal) {
#pragma unroll
          for (int n = 0; n < 4; ++n)
            C[row * N + (n0 + wc * 64 + n * 16 + cidx)] = (_Float16)acc[m][n][rr];
        }
      }
  }
}

// ==================== heads: S/norms from QG, softmax, WeffT. One block per (b,h) ====================
__global__ __launch_bounds__(256)
void k_heads(const _Float16* __restrict__ QG, const _Float16* __restrict__ w16,
             const _Float16* __restrict__ wvT, const float* __restrict__ temperature,
             _Float16* __restrict__ weffT)
{
  const int b = blockIdx.x >> 4, h = blockIdx.x & 15;
  const int tid = threadIdx.x;
  const int w = tid >> 6, lane = tid & 63;
  const int g = lane >> 4, c = lane & 15;

  __shared__ float red[4][48 * 48];
  __shared__ float redss[4][2][48];
  __shared__ float inv[2][48];
  __shared__ _Float16 Pb[48 * 64];

  const _Float16* QGq = QG + (long)b * 1179648 + (long)(h * 48) * 768;
  const _Float16* QGk = QGq + 768L * 768;
  const _Float16* Wq  = w16 + (long)(h * 48) * 768;
  const _Float16* Wk  = w16 + (long)(768 + h * 48) * 768;

  f32x4 aS[3][3] = {};
  f32x4 aq[3] = {};
  f32x4 ak[3] = {};
  for (int ks = w * 6; ks < w * 6 + 6; ++ks) {
    const int k0 = ks * 32 + g * 8;
    half8 t1[3], t3[3], wqf[3], wkf[3];
#pragma unroll
    for (int m = 0; m < 3; ++m) {
      const long ro = (long)(m * 16 + c) * 768 + k0;
      t1[m]  = *(const half8*)(QGq + ro);
      t3[m]  = *(const half8*)(QGk + ro);
      wqf[m] = *(const half8*)(Wq + ro);
      wkf[m] = *(const half8*)(Wk + ro);
    }
#pragma unroll
    for (int m = 0; m < 3; ++m) {
      aq[m] = MFMA_F16(t1[m], wqf[m], aq[m]);
      ak[m] = MFMA_F16(t3[m], wkf[m], ak[m]);
#pragma unroll
      for (int n = 0; n < 3; ++n)
        aS[m][n] = MFMA_F16(t1[m], wkf[n], aS[m][n]);
    }
  }

#pragma unroll
  for (int m = 0; m < 3; ++m) {
#pragma unroll
    for (int n = 0; n < 3; ++n)
#pragma unroll
      for (int rr = 0; rr < 4; ++rr)
        red[w][(m * 16 + g * 4 + rr) * 48 + n * 16 + c] = aS[m][n][rr];
#pragma unroll
    for (int rr = 0; rr < 4; ++rr)
      if (c == g * 4 + rr) {
        redss[w][0][m * 16 + c] = aq[m][rr];
        redss[w][1][m * 16 + c] = ak[m][rr];
      }
  }
  __syncthreads();

  if (tid < 96) {
    const int is_k = tid / 48, d = tid % 48;
    const float s = redss[0][is_k][d] + redss[1][is_k][d] + redss[2][is_k][d] + redss[3][is_k][d];
    inv[is_k][d] = 1.0f / fmaxf(sqrtf(s), 1e-12f);
  }
  __syncthreads();

  if (tid < 48) {
    const int d = tid;
    const float iq = inv[0][d] * temperature[h];
    float rowv[48];
    float mx = -3.0e38f;
#pragma unroll
    for (int e = 0; e < 48; ++e) {
      const int idx = d * 48 + e;
      float t = (red[0][idx] + red[1][idx] + red[2][idx] + red[3][idx]) * iq * inv[1][e];
      rowv[e] = t;
      mx = fmaxf(mx, t);
    }
    float sum = 0.f;
#pragma unroll
    for (int e = 0; e < 48; ++e) {
      const float pv = __expf(rowv[e] - mx);
      rowv[e] = pv;
      sum += pv;
    }
    const float is = 1.0f / sum;
#pragma unroll
    for (int e = 0; e < 48; ++e)
      Pb[d * 64 + e] = (_Float16)(rowv[e] * is);
#pragma unroll
    for (int e = 48; e < 64; ++e)
      Pb[d * 64 + e] = (_Float16)0.f;
  }
  __syncthreads();

  half8 pf[3][2];
#pragma unroll
  for (int nf = 0; nf < 3; ++nf)
#pragma unroll
    for (int ks = 0; ks < 2; ++ks)
      pf[nf][ks] = *(const half8*)&Pb[(nf * 16 + c) * 64 + ks * 32 + g * 8];

  const _Float16* wvh = wvT + (long)h * 768 * 64;
  _Float16* wout = weffT + (long)b * 589824 + h * 48;

  for (int m = 0; m < 12; ++m) {
    const int f0 = w * 192 + m * 16;
    half8 va[2];
#pragma unroll
    for (int ks = 0; ks < 2; ++ks)
      va[ks] = *(const half8*)&wvh[(long)(f0 + c) * 64 + ks * 32 + g * 8];
    f32x4 a3[3] = {};
#pragma unroll
    for (int ks = 0; ks < 2; ++ks)
#pragma unroll
      for (int nf = 0; nf < 3; ++nf)
        a3[nf] = MFMA_F16(va[ks], pf[nf][ks], a3[nf]);
#pragma unroll
    for (int nf = 0; nf < 3; ++nf)
#pragma unroll
      for (int rr = 0; rr < 4; ++rr)
        wout[(long)(f0 + g * 4 + rr) * 768 + nf * 16 + c] = (_Float16)a3[nf][rr];
  }
}

// -------------------- launch --------------------
extern "C" void kernel_launch(void* const* d_in, const int* in_sizes, int n_in,
                              void* d_out, int out_size, void* d_ws, size_t ws_size,
                              hipStream_t stream)
{
  (void)in_sizes; (void)n_in; (void)out_size; (void)ws_size;
  const float* x      = (const float*)d_in[0];
  const float* w_qkv  = (const float*)d_in[1];
  const float* temp   = (const float*)d_in[2];
  const float* w_proj = (const float*)d_in[3];
  const float* b_proj = (const float*)d_in[4];
  float* out = (float*)d_out;

  // ws layout (bytes): x16, xT, G, QG, weffT, wfin, w16, wp16, wvT
  char* ws = (char*)d_ws;
  _Float16* x16   = (_Float16*)(ws);
  _Float16* xT    = (_Float16*)(ws + 77070336L);
  _Float16* G     = (_Float16*)(ws + 154140672L);
  _Float16* QG    = (_Float16*)(ws + 173015040L);
  _Float16* weffT = (_Float16*)(ws + 210763776L);
  _Float16* wfin  = (_Float16*)(ws + 229638144L);
  _Float16* w16   = (_Float16*)(ws + 248512512L);
  _Float16* wp16  = (_Float16*)(ws + 252051456L);
  _Float16* wvT   = (_Float16*)(ws + 253231104L);

  // x convert + transpose (blocks 0..9407) and weight converts (blocks 9408..9919)
  k_cvtx<<<9920, 256, 0, stream>>>(x, x16, xT, w_qkv, w_proj, w16, wp16, wvT);
  // G_b = xT_b . xT_b^T (symmetric), 8-wave BK=64
  k_gram<<<336, 512, 0, stream>>>(xT, G);
  // QG_b = w16[0:1536] . G_b  (8-phase 256^2)
  k_gemm8p<false><<<288, 512, 0, stream>>>(w16, G, QG, nullptr,
                                           6, 3, 1536, 0, 589824, 1179648, 768, 768);
  // per (b,h): S, norms, softmax, WeffT
  k_heads<<<256, 256, 0, stream>>>(QG, w16, wvT, temp, weffT);
  // wfin_b = Wp . Weff_b
  k_g128<false><<<576, 256, 0, stream>>>(wp16, weffT, wfin, nullptr,
                                         6, 6, 768, 0, 589824, 589824, 768, 768);
  // out_b[t][o] = x16_b[t,:] . wfin_b[o,:] + bias  (fp32, 8-phase, M-tail masked)
  k_gemm8p<true><<<624, 512, 0, stream>>>(x16, wfin, out, b_proj,
                                          13, 3, 3136, 3136L * 768, 589824, 3136L * 768,
                                          768, 768);
}